// Round 3
// baseline (640.384 us; speedup 1.0000x reference)
//
#include <hip/hip_runtime.h>
#include <cstdint>
#include <cstddef>

// Geometry: x (16,32,128,128) fp32 -> G=2 groups, F=256 features/group
// (= 8 batch-of-group * 32 ch), N=16384 positions, 8 heads/group, dim_head=64.
// Whole block collapses to: C[g]=F·F^T Gram; sim=Wq_h·C·Wk_h^T; attn=softmax;
// M[g] = (Wout·blockdiag_h(attn))·Wv; out = M[g]·f + bout.  All fp32.
constexpr int NP = 16384;

// ws layout (fp32 element offsets)
constexpr size_t OFF_C  = 0;        // C[2][256][256]       131072
constexpr size_t OFF_T  = 131072;   // T[16][64][256]       262144
constexpr size_t OFF_AT = 393216;   // sim/attn[16][64][64]  65536
constexpr size_t OFF_WE = 458752;   // WeT[2][512][256]     262144
constexpr size_t OFF_MT = 720896;   // Mt[2][256][256]      131072
// total 851968 floats = 3.25 MiB

// ---------------------------------------------------------------------------
// K1: C[g] += X * X^T over a K-chunk of 256 positions.
// X is the (256 x 16384) row-major feature view of x for group g.
// 128x128 C-tile per block, 4 waves, 8x8 micro-tile/lane, fp32 atomics out.
__global__ __launch_bounds__(256, 2) void k1_gram(const float* __restrict__ x,
                                                  float* __restrict__ Cmat) {
  __shared__ float As[128 * 33];
  __shared__ float Bs[128 * 33];
  const int kc   = blockIdx.x;          // 64 chunks of 256
  const int tile = blockIdx.y;          // 4: 2x2 tiles of 128
  const int g    = blockIdx.z;          // 2
  const int i0 = (tile >> 1) * 128;
  const int j0 = (tile & 1) * 128;
  const float* __restrict__ Xg = x + (size_t)g * 256 * NP;
  const int tid  = threadIdx.x;
  const int lane = tid & 63;
  const int w    = tid >> 6;
  const int wy = (w >> 1) * 64;
  const int wx = (w & 1) * 64;
  const int ly = (lane >> 3) * 8;
  const int lx = (lane & 7) * 8;

  float acc[8][8];
#pragma unroll
  for (int e = 0; e < 8; ++e)
#pragma unroll
    for (int f = 0; f < 8; ++f) acc[e][f] = 0.f;

  const int k8   = (tid & 3) * 8;   // 4 chunks of 8 floats = 32 k per stage
  const int rowb = tid >> 2;        // 0..63
  const int k0 = kc * 256;

  for (int s = 0; s < 8; ++s) {
    const int ks = k0 + s * 32;
#pragma unroll
    for (int pass = 0; pass < 2; ++pass) {
      const int row = rowb + pass * 64;
      {
        const size_t e0 = (size_t)(i0 + row) * NP + ks + k8;
        float4 a = *(const float4*)(Xg + e0);
        float4 b = *(const float4*)(Xg + e0 + 4);
        float* d = &As[row * 33 + k8];
        d[0]=a.x; d[1]=a.y; d[2]=a.z; d[3]=a.w;
        d[4]=b.x; d[5]=b.y; d[6]=b.z; d[7]=b.w;
      }
      {
        const size_t e0 = (size_t)(j0 + row) * NP + ks + k8;
        float4 a = *(const float4*)(Xg + e0);
        float4 b = *(const float4*)(Xg + e0 + 4);
        float* d = &Bs[row * 33 + k8];
        d[0]=a.x; d[1]=a.y; d[2]=a.z; d[3]=a.w;
        d[4]=b.x; d[5]=b.y; d[6]=b.z; d[7]=b.w;
      }
    }
    __syncthreads();
#pragma unroll 2
    for (int kk = 0; kk < 32; ++kk) {
      float a[8], b[8];
#pragma unroll
      for (int e = 0; e < 8; ++e) a[e] = As[(wy + ly + e) * 33 + kk];
#pragma unroll
      for (int f = 0; f < 8; ++f) b[f] = Bs[(wx + lx + f) * 33 + kk];
#pragma unroll
      for (int e = 0; e < 8; ++e)
#pragma unroll
        for (int f = 0; f < 8; ++f) acc[e][f] += a[e] * b[f];
    }
    __syncthreads();
  }
  float* Cg = Cmat + (size_t)g * 65536;
#pragma unroll
  for (int e = 0; e < 8; ++e)
#pragma unroll
    for (int f = 0; f < 8; ++f)
      atomicAdd(&Cg[(i0 + wy + ly + e) * 256 + (j0 + wx + lx + f)],
                acc[e][f]);
}

// ---------------------------------------------------------------------------
// K2: T[bh][i][a] = sum_b Wq[hh*64+i][b] * C[g][b][a].  Lanes = a (coalesced),
// Wq rows via uniform scalar fp32 loads.
__global__ __launch_bounds__(256) void k2_T(const float* __restrict__ Wq,
                                            const float* __restrict__ Cmat,
                                            float* __restrict__ T) {
  const int bh = blockIdx.x;   // 16
  const int ic = blockIdx.y;   // 16 -> 4 rows each
  const int g = bh >> 3, hh = bh & 7;
  const int tid = threadIdx.x;
  const float* __restrict__ Cg = Cmat + (size_t)g * 65536;
  const int r0 = hh * 64 + ic * 4;
  float acc[4] = {0.f, 0.f, 0.f, 0.f};
  for (int b = 0; b < 256; ++b) {
    const float cv = Cg[(size_t)b * 256 + tid];
#pragma unroll
    for (int ii = 0; ii < 4; ++ii)
      acc[ii] += Wq[(size_t)(r0 + ii) * 256 + b] * cv;
  }
#pragma unroll
  for (int ii = 0; ii < 4; ++ii)
    T[((size_t)bh * 64 + ic * 4 + ii) * 256 + tid] = acc[ii];
}

// ---------------------------------------------------------------------------
// K3: sim[bh][i][j] = 0.125 * sum_a T[bh][i][a] * Wk[hh*64+j][a].
// Lanes = i; T staged in LDS with rotate-within-32 swizzle (row stride 256
// would put all 64 lanes on one bank); Wk rows via uniform scalar loads.
__global__ __launch_bounds__(256) void k3_sim(const float* __restrict__ Wkv,
                                              const float* __restrict__ T,
                                              float* __restrict__ simattn) {
  __shared__ float Ts[64 * 256];  // 64 KiB
  const int bh = blockIdx.x;  // 16
  const int jc = blockIdx.y;  // 4 -> 16 j each
  const int hh = bh & 7;
  const int tid = threadIdx.x;
  {
    const int f4i = tid & 63;   // 64 float4 chunks per 256-row
    const int rwb = tid >> 6;   // 0..3
    for (int pass = 0; pass < 16; ++pass) {
      const int row = rwb + pass * 4;
      float4 v = *(const float4*)(T + ((size_t)bh * 64 + row) * 256 + f4i * 4);
      const int a0 = f4i * 4;
      const float vv[4] = {v.x, v.y, v.z, v.w};
#pragma unroll
      for (int e = 0; e < 4; ++e) {
        const int a = a0 + e;
        Ts[row * 256 + (a & ~31) + ((a + row) & 31)] = vv[e];
      }
    }
  }
  __syncthreads();
  const int i  = tid & 63;
  const int jq = tid >> 6;
  const int jb = jc * 16 + jq * 4;
  float acc[4] = {0.f, 0.f, 0.f, 0.f};
  for (int a = 0; a < 256; ++a) {
    const float tv = Ts[i * 256 + (a & ~31) + ((a + i) & 31)];
#pragma unroll
    for (int jj = 0; jj < 4; ++jj)
      acc[jj] += Wkv[(size_t)(hh * 64 + jb + jj) * 256 + a] * tv;
  }
#pragma unroll
  for (int jj = 0; jj < 4; ++jj)
    simattn[((size_t)bh * 64 + i) * 64 + jb + jj] = acc[jj] * 0.125f;
}

// K3b: row softmax over j (in place), one lane per row.
__global__ __launch_bounds__(64) void k3b_softmax(float* __restrict__ simattn) {
  const int bh = blockIdx.x;
  const int i  = threadIdx.x;
  float* row = simattn + ((size_t)bh * 64 + i) * 64;
  float v[64];
  float m = -1e30f;
#pragma unroll
  for (int j = 0; j < 64; ++j) { v[j] = row[j]; m = fmaxf(m, v[j]); }
  float s = 0.f;
#pragma unroll
  for (int j = 0; j < 64; ++j) { v[j] = __expf(v[j] - m); s += v[j]; }
  const float inv = 1.0f / s;
#pragma unroll
  for (int j = 0; j < 64; ++j) row[j] = v[j] * inv;
}

// ---------------------------------------------------------------------------
// K4: WeT[g][hh*64+j][co] = sum_i Wout[co][hh*64+i] * attn[bh][i][j].
// Wout head-block staged in LDS, transposed access via rotate-by-co swizzle.
__global__ __launch_bounds__(256) void k4_we(const float* __restrict__ Wout,
                                             const float* __restrict__ attn,
                                             float* __restrict__ WeT) {
  __shared__ float WL[256 * 64];  // 64 KiB
  const int jc = blockIdx.x;  // 8 -> 8 j each
  const int hh = blockIdx.y;  // 8
  const int g  = blockIdx.z;  // 2
  const int bh = g * 8 + hh;
  const int tid = threadIdx.x;  // co lane
  {
    const int f4i = tid & 15;  // 16 float4 chunks per 64-col slab
    const int cb  = tid >> 4;  // 0..15
    for (int pass = 0; pass < 16; ++pass) {
      const int co = cb + pass * 16;
      float4 v = *(const float4*)(Wout + (size_t)co * 512 + hh * 64 + f4i * 4);
      const int a0 = f4i * 4;
      const float vv[4] = {v.x, v.y, v.z, v.w};
#pragma unroll
      for (int e = 0; e < 4; ++e)
        WL[co * 64 + ((a0 + e + co) & 63)] = vv[e];
    }
  }
  __syncthreads();
  const int jb = jc * 8;
  float acc[8] = {0.f, 0.f, 0.f, 0.f, 0.f, 0.f, 0.f, 0.f};
  for (int i = 0; i < 64; ++i) {
    const float wv = WL[tid * 64 + ((i + tid) & 63)];
#pragma unroll
    for (int je = 0; je < 8; ++je)
      acc[je] += attn[((size_t)bh * 64 + i) * 64 + jb + je] * wv;
  }
#pragma unroll
  for (int je = 0; je < 8; ++je)
    WeT[(size_t)g * 131072 + (size_t)(hh * 64 + jb + je) * 256 + tid] =
        acc[je];
}

// ---------------------------------------------------------------------------
// K5: Mt[g][b][co] = sum_o WeT[g][o][co] * Wv[o][b]; Wv = Wkv rows 512..1023.
__global__ __launch_bounds__(256) void k5_M(const float* __restrict__ Wkv,
                                            const float* __restrict__ WeT,
                                            float* __restrict__ Mt) {
  const int bc = blockIdx.x;  // 64 -> 4 b each
  const int g  = blockIdx.y;
  const int tid = threadIdx.x;  // co lane
  const int b0 = bc * 4;
  const float* __restrict__ Weg = WeT + (size_t)g * 131072;
  float acc[4] = {0.f, 0.f, 0.f, 0.f};
  for (int o = 0; o < 512; ++o) {
    const float wv = Weg[(size_t)o * 256 + tid];
    const float* __restrict__ vr = Wkv + (size_t)(512 + o) * 256 + b0;
    acc[0] += vr[0] * wv;
    acc[1] += vr[1] * wv;
    acc[2] += vr[2] * wv;
    acc[3] += vr[3] * wv;
  }
#pragma unroll
  for (int be = 0; be < 4; ++be)
    Mt[(size_t)g * 65536 + (size_t)(b0 + be) * 256 + tid] = acc[be];
}

// ---------------------------------------------------------------------------
// K6: out[(g*256+co)*NP + p] = bout[co] + sum_b Mt[g][b][co]*f[g,p,b].
// 64-position chunk staged to LDS; lane = p, wave = 64-co slab; Mt rows via
// uniform scalar loads (consecutive fp32 per b).  fp32 output.
__global__ __launch_bounds__(256, 2) void k6_apply(const float* __restrict__ x,
                                                   const float* __restrict__ Mt,
                                                   const float* __restrict__ bout,
                                                   float* __restrict__ out) {
  __shared__ float Fs[256 * 64];  // 64 KiB
  const int pc = blockIdx.x;  // 256 chunks of 64 positions
  const int g  = blockIdx.y;
  const int p0 = pc * 64;
  const float* __restrict__ Xg = x + (size_t)g * 256 * NP;
  const int tid = threadIdx.x;
  {
    const int f8i = tid & 7;   // 8 chunks of 8 floats = 64 p
    const int rb  = tid >> 3;  // 0..31
    for (int pass = 0; pass < 8; ++pass) {
      const int row = rb + pass * 32;
      const size_t e0 = (size_t)row * NP + p0 + f8i * 8;
      float4 a = *(const float4*)(Xg + e0);
      float4 b = *(const float4*)(Xg + e0 + 4);
      float* d = &Fs[row * 64 + f8i * 8];
      d[0]=a.x; d[1]=a.y; d[2]=a.z; d[3]=a.w;
      d[4]=b.x; d[5]=b.y; d[6]=b.z; d[7]=b.w;
    }
  }
  __syncthreads();
  const int p  = tid & 63;
  const int cq = __builtin_amdgcn_readfirstlane(tid >> 6);  // wave-uniform
  const float* __restrict__ Mg = Mt + (size_t)g * 65536 + cq * 64;
  float acc[64];
#pragma unroll
  for (int ce = 0; ce < 64; ++ce) acc[ce] = bout[cq * 64 + ce];
  for (int b = 0; b < 256; ++b) {
    const float fv = Fs[b * 64 + p];
    const float* __restrict__ mrow = Mg + (size_t)b * 256;
#pragma unroll
    for (int ce = 0; ce < 64; ++ce) acc[ce] += mrow[ce] * fv;
  }
  float* og = out + ((size_t)(g * 256 + cq * 64)) * NP + p0 + p;
#pragma unroll
  for (int ce = 0; ce < 64; ++ce) og[(size_t)ce * NP] = acc[ce];
}

// ---------------------------------------------------------------------------
extern "C" void kernel_launch(void* const* d_in, const int* in_sizes, int n_in,
                              void* d_out, int out_size, void* d_ws,
                              size_t ws_size, hipStream_t stream) {
  const float* x    = (const float*)d_in[0];
  const float* Wq   = (const float*)d_in[1];
  const float* Wkv  = (const float*)d_in[2];
  const float* Wout = (const float*)d_in[3];
  const float* bout = (const float*)d_in[4];
  float* out = (float*)d_out;
  float* ws  = (float*)d_ws;

  float* C   = ws + OFF_C;
  float* T   = ws + OFF_T;
  float* att = ws + OFF_AT;
  float* WeT = ws + OFF_WE;
  float* Mt  = ws + OFF_MT;

  // C is accumulated with atomics; ws is poisoned before every call.
  hipMemsetAsync(C, 0, 131072 * sizeof(float), stream);

  k1_gram<<<dim3(64, 4, 2), 256, 0, stream>>>(x, C);
  k2_T<<<dim3(16, 16), 256, 0, stream>>>(Wq, C, T);
  k3_sim<<<dim3(16, 4), 256, 0, stream>>>(Wkv, T, att);
  k3b_softmax<<<dim3(16), 64, 0, stream>>>(att);
  k4_we<<<dim3(8, 8, 2), 256, 0, stream>>>(Wout, att, WeT);
  k5_M<<<dim3(64, 2), 256, 0, stream>>>(Wkv, WeT, Mt);
  k6_apply<<<dim3(256, 2), 256, 0, stream>>>(x, Mt, bout, out);
}

// Round 4
// 622.175 us; speedup vs baseline: 1.0293x; 1.0293x over previous
//
#include <hip/hip_runtime.h>
#include <cstdint>
#include <cstddef>

// Geometry: x (16,32,128,128) fp32 -> G=2 groups, F=256 features/group
// (= 8 batch-of-group * 32 ch), N=16384 positions, 8 heads/group, dim_head=64.
// Whole block collapses to: C[g]=F·F^T Gram; sim=Wq_h·C·Wk_h^T; attn=softmax;
// M[g] = (Wout·blockdiag_h(attn))·Wv; out = M[g]·f + bout.  All fp32.
constexpr int NP = 16384;

// ws layout (fp32 element offsets)
constexpr size_t OFF_C  = 0;        // C[2][256][256]       131072
constexpr size_t OFF_T  = 131072;   // T[16][64][256]       262144
constexpr size_t OFF_AT = 393216;   // sim/attn[16][64][64]  65536
constexpr size_t OFF_WE = 458752;   // WeT[2][512][256]     262144
constexpr size_t OFF_MT = 720896;   // Mt[2][256][256]      131072
// total 851968 floats = 3.25 MiB

// ---------------------------------------------------------------------------
// K1: C[g] += X * X^T over a K-chunk of 256 positions.
// X is the (256 x 16384) row-major feature view of x for group g.
// 128x128 C-tile per block, 4 waves, 8x8 micro-tile/lane, fp32 atomics out.
// LDS tiles stored TRANSPOSED [kk][row] (pad 132) so each lane's 8 operands
// are contiguous -> ds_read_b128.  NO launch_bounds min-occupancy arg: with
// (256,2) the compiler capped VGPR at 64 and spilled the 64-float acc
// (R3 counters: WRITE_SIZE 256 MB of spill, VALUBusy 8%).
__global__ __launch_bounds__(256) void k1_gram(const float* __restrict__ x,
                                               float* __restrict__ Cmat) {
  __shared__ float As[32 * 132];   // [kk][row0..127], pad 132 (16B-aligned)
  __shared__ float Bs[32 * 132];
  const int kc   = blockIdx.x;          // 64 chunks of 256
  const int tile = blockIdx.y;          // 4: 2x2 tiles of 128
  const int g    = blockIdx.z;          // 2
  const int i0 = (tile >> 1) * 128;
  const int j0 = (tile & 1) * 128;
  const float* __restrict__ Xg = x + (size_t)g * 256 * NP;
  const int tid  = threadIdx.x;
  const int lane = tid & 63;
  const int w    = tid >> 6;
  const int wy = (w >> 1) * 64;
  const int wx = (w & 1) * 64;
  const int ly = (lane >> 3) * 8;
  const int lx = (lane & 7) * 8;

  float acc[8][8];
#pragma unroll
  for (int e = 0; e < 8; ++e)
#pragma unroll
    for (int f = 0; f < 8; ++f) acc[e][f] = 0.f;

  const int k8   = (tid & 3) * 8;   // 4 chunks of 8 floats = 32 k per stage
  const int rowb = tid >> 2;        // 0..63
  const int k0 = kc * 256;

  for (int s = 0; s < 8; ++s) {
    const int ks = k0 + s * 32;
#pragma unroll
    for (int pass = 0; pass < 2; ++pass) {
      const int row = rowb + pass * 64;
      {
        const size_t e0 = (size_t)(i0 + row) * NP + ks + k8;
        float4 a = *(const float4*)(Xg + e0);
        float4 b = *(const float4*)(Xg + e0 + 4);
        As[(k8 + 0) * 132 + row] = a.x;
        As[(k8 + 1) * 132 + row] = a.y;
        As[(k8 + 2) * 132 + row] = a.z;
        As[(k8 + 3) * 132 + row] = a.w;
        As[(k8 + 4) * 132 + row] = b.x;
        As[(k8 + 5) * 132 + row] = b.y;
        As[(k8 + 6) * 132 + row] = b.z;
        As[(k8 + 7) * 132 + row] = b.w;
      }
      {
        const size_t e0 = (size_t)(j0 + row) * NP + ks + k8;
        float4 a = *(const float4*)(Xg + e0);
        float4 b = *(const float4*)(Xg + e0 + 4);
        Bs[(k8 + 0) * 132 + row] = a.x;
        Bs[(k8 + 1) * 132 + row] = a.y;
        Bs[(k8 + 2) * 132 + row] = a.z;
        Bs[(k8 + 3) * 132 + row] = a.w;
        Bs[(k8 + 4) * 132 + row] = b.x;
        Bs[(k8 + 5) * 132 + row] = b.y;
        Bs[(k8 + 6) * 132 + row] = b.z;
        Bs[(k8 + 7) * 132 + row] = b.w;
      }
    }
    __syncthreads();
#pragma unroll 4
    for (int kk = 0; kk < 32; ++kk) {
      const float* __restrict__ ar = &As[kk * 132 + wy + ly];
      const float* __restrict__ br = &Bs[kk * 132 + wx + lx];
      float4 a0 = *(const float4*)(ar);
      float4 a1 = *(const float4*)(ar + 4);
      float4 b0 = *(const float4*)(br);
      float4 b1 = *(const float4*)(br + 4);
      const float av[8] = {a0.x, a0.y, a0.z, a0.w, a1.x, a1.y, a1.z, a1.w};
      const float bv[8] = {b0.x, b0.y, b0.z, b0.w, b1.x, b1.y, b1.z, b1.w};
#pragma unroll
      for (int e = 0; e < 8; ++e)
#pragma unroll
        for (int f = 0; f < 8; ++f) acc[e][f] += av[e] * bv[f];
    }
    __syncthreads();
  }
  float* Cg = Cmat + (size_t)g * 65536;
#pragma unroll
  for (int e = 0; e < 8; ++e)
#pragma unroll
    for (int f = 0; f < 8; ++f)
      atomicAdd(&Cg[(i0 + wy + ly + e) * 256 + (j0 + wx + lx + f)],
                acc[e][f]);
}

// ---------------------------------------------------------------------------
// K2: T[bh][i][a] = sum_b Wq[hh*64+i][b] * C[g][b][a].  Lanes = a (coalesced),
// Wq rows via uniform scalar fp32 loads.
__global__ __launch_bounds__(256) void k2_T(const float* __restrict__ Wq,
                                            const float* __restrict__ Cmat,
                                            float* __restrict__ T) {
  const int bh = blockIdx.x;   // 16
  const int ic = blockIdx.y;   // 16 -> 4 rows each
  const int g = bh >> 3, hh = bh & 7;
  const int tid = threadIdx.x;
  const float* __restrict__ Cg = Cmat + (size_t)g * 65536;
  const int r0 = hh * 64 + ic * 4;
  float acc[4] = {0.f, 0.f, 0.f, 0.f};
  for (int b = 0; b < 256; ++b) {
    const float cv = Cg[(size_t)b * 256 + tid];
#pragma unroll
    for (int ii = 0; ii < 4; ++ii)
      acc[ii] += Wq[(size_t)(r0 + ii) * 256 + b] * cv;
  }
#pragma unroll
  for (int ii = 0; ii < 4; ++ii)
    T[((size_t)bh * 64 + ic * 4 + ii) * 256 + tid] = acc[ii];
}

// ---------------------------------------------------------------------------
// K3: sim[bh][i][j] = 0.125 * sum_a T[bh][i][a] * Wk[hh*64+j][a].
// Lanes = i; T staged in LDS with rotate-within-32 swizzle (row stride 256
// would put all 64 lanes on one bank); Wk rows via uniform scalar loads.
__global__ __launch_bounds__(256) void k3_sim(const float* __restrict__ Wkv,
                                              const float* __restrict__ T,
                                              float* __restrict__ simattn) {
  __shared__ float Ts[64 * 256];  // 64 KiB
  const int bh = blockIdx.x;  // 16
  const int jc = blockIdx.y;  // 4 -> 16 j each
  const int hh = bh & 7;
  const int tid = threadIdx.x;
  {
    const int f4i = tid & 63;   // 64 float4 chunks per 256-row
    const int rwb = tid >> 6;   // 0..3
    for (int pass = 0; pass < 16; ++pass) {
      const int row = rwb + pass * 4;
      float4 v = *(const float4*)(T + ((size_t)bh * 64 + row) * 256 + f4i * 4);
      const int a0 = f4i * 4;
      const float vv[4] = {v.x, v.y, v.z, v.w};
#pragma unroll
      for (int e = 0; e < 4; ++e) {
        const int a = a0 + e;
        Ts[row * 256 + (a & ~31) + ((a + row) & 31)] = vv[e];
      }
    }
  }
  __syncthreads();
  const int i  = tid & 63;
  const int jq = tid >> 6;
  const int jb = jc * 16 + jq * 4;
  float acc[4] = {0.f, 0.f, 0.f, 0.f};
  for (int a = 0; a < 256; ++a) {
    const float tv = Ts[i * 256 + (a & ~31) + ((a + i) & 31)];
#pragma unroll
    for (int jj = 0; jj < 4; ++jj)
      acc[jj] += Wkv[(size_t)(hh * 64 + jb + jj) * 256 + a] * tv;
  }
#pragma unroll
  for (int jj = 0; jj < 4; ++jj)
    simattn[((size_t)bh * 64 + i) * 64 + jb + jj] = acc[jj] * 0.125f;
}

// K3b: row softmax over j (in place), one lane per row.
__global__ __launch_bounds__(64) void k3b_softmax(float* __restrict__ simattn) {
  const int bh = blockIdx.x;
  const int i  = threadIdx.x;
  float* row = simattn + ((size_t)bh * 64 + i) * 64;
  float v[64];
  float m = -1e30f;
#pragma unroll
  for (int j = 0; j < 64; ++j) { v[j] = row[j]; m = fmaxf(m, v[j]); }
  float s = 0.f;
#pragma unroll
  for (int j = 0; j < 64; ++j) { v[j] = __expf(v[j] - m); s += v[j]; }
  const float inv = 1.0f / s;
#pragma unroll
  for (int j = 0; j < 64; ++j) row[j] = v[j] * inv;
}

// ---------------------------------------------------------------------------
// K4: WeT[g][hh*64+j][co] = sum_i Wout[co][hh*64+i] * attn[bh][i][j].
// Wout head-block staged in LDS, transposed access via rotate-by-co swizzle.
__global__ __launch_bounds__(256) void k4_we(const float* __restrict__ Wout,
                                             const float* __restrict__ attn,
                                             float* __restrict__ WeT) {
  __shared__ float WL[256 * 64];  // 64 KiB
  const int jc = blockIdx.x;  // 8 -> 8 j each
  const int hh = blockIdx.y;  // 8
  const int g  = blockIdx.z;  // 2
  const int bh = g * 8 + hh;
  const int tid = threadIdx.x;  // co lane
  {
    const int f4i = tid & 15;  // 16 float4 chunks per 64-col slab
    const int cb  = tid >> 4;  // 0..15
    for (int pass = 0; pass < 16; ++pass) {
      const int co = cb + pass * 16;
      float4 v = *(const float4*)(Wout + (size_t)co * 512 + hh * 64 + f4i * 4);
      const int a0 = f4i * 4;
      const float vv[4] = {v.x, v.y, v.z, v.w};
#pragma unroll
      for (int e = 0; e < 4; ++e)
        WL[co * 64 + ((a0 + e + co) & 63)] = vv[e];
    }
  }
  __syncthreads();
  const int jb = jc * 8;
  float acc[8] = {0.f, 0.f, 0.f, 0.f, 0.f, 0.f, 0.f, 0.f};
  for (int i = 0; i < 64; ++i) {
    const float wv = WL[tid * 64 + ((i + tid) & 63)];
#pragma unroll
    for (int je = 0; je < 8; ++je)
      acc[je] += attn[((size_t)bh * 64 + i) * 64 + jb + je] * wv;
  }
#pragma unroll
  for (int je = 0; je < 8; ++je)
    WeT[(size_t)g * 131072 + (size_t)(hh * 64 + jb + je) * 256 + tid] =
        acc[je];
}

// ---------------------------------------------------------------------------
// K5: Mt[g][b][co] = sum_o WeT[g][o][co] * Wv[o][b]; Wv = Wkv rows 512..1023.
__global__ __launch_bounds__(256) void k5_M(const float* __restrict__ Wkv,
                                            const float* __restrict__ WeT,
                                            float* __restrict__ Mt) {
  const int bc = blockIdx.x;  // 64 -> 4 b each
  const int g  = blockIdx.y;
  const int tid = threadIdx.x;  // co lane
  const int b0 = bc * 4;
  const float* __restrict__ Weg = WeT + (size_t)g * 131072;
  float acc[4] = {0.f, 0.f, 0.f, 0.f};
  for (int o = 0; o < 512; ++o) {
    const float wv = Weg[(size_t)o * 256 + tid];
    const float* __restrict__ vr = Wkv + (size_t)(512 + o) * 256 + b0;
    acc[0] += vr[0] * wv;
    acc[1] += vr[1] * wv;
    acc[2] += vr[2] * wv;
    acc[3] += vr[3] * wv;
  }
#pragma unroll
  for (int be = 0; be < 4; ++be)
    Mt[(size_t)g * 65536 + (size_t)(b0 + be) * 256 + tid] = acc[be];
}

// ---------------------------------------------------------------------------
// K6: out[(g*256+co)*NP + p] = bout[co] + sum_b Mt[g][b][co]*f[g,p,b].
// 64-position chunk staged to LDS; lane = p, wave = 64-co slab; Mt rows via
// uniform scalar loads (consecutive fp32 per b).  fp32 output.
// Plain launch_bounds: with (256,2) the acc[64] spilled (see k1 note).
__global__ __launch_bounds__(256) void k6_apply(const float* __restrict__ x,
                                                const float* __restrict__ Mt,
                                                const float* __restrict__ bout,
                                                float* __restrict__ out) {
  __shared__ float Fs[256 * 64];  // 64 KiB
  const int pc = blockIdx.x;  // 256 chunks of 64 positions
  const int g  = blockIdx.y;
  const int p0 = pc * 64;
  const float* __restrict__ Xg = x + (size_t)g * 256 * NP;
  const int tid = threadIdx.x;
  {
    const int f8i = tid & 7;   // 8 chunks of 8 floats = 64 p
    const int rb  = tid >> 3;  // 0..31
    for (int pass = 0; pass < 8; ++pass) {
      const int row = rb + pass * 32;
      const size_t e0 = (size_t)row * NP + p0 + f8i * 8;
      float4 a = *(const float4*)(Xg + e0);
      float4 b = *(const float4*)(Xg + e0 + 4);
      float* d = &Fs[row * 64 + f8i * 8];
      d[0]=a.x; d[1]=a.y; d[2]=a.z; d[3]=a.w;
      d[4]=b.x; d[5]=b.y; d[6]=b.z; d[7]=b.w;
    }
  }
  __syncthreads();
  const int p  = tid & 63;
  const int cq = __builtin_amdgcn_readfirstlane(tid >> 6);  // wave-uniform
  const float* __restrict__ Mg = Mt + (size_t)g * 65536 + cq * 64;
  float acc[64];
#pragma unroll
  for (int ce = 0; ce < 64; ++ce) acc[ce] = bout[cq * 64 + ce];
  for (int b = 0; b < 256; ++b) {
    const float fv = Fs[b * 64 + p];
    const float* __restrict__ mrow = Mg + (size_t)b * 256;
#pragma unroll
    for (int ce = 0; ce < 64; ++ce) acc[ce] += mrow[ce] * fv;
  }
  float* og = out + ((size_t)(g * 256 + cq * 64)) * NP + p0 + p;
#pragma unroll
  for (int ce = 0; ce < 64; ++ce) og[(size_t)ce * NP] = acc[ce];
}

// ---------------------------------------------------------------------------
extern "C" void kernel_launch(void* const* d_in, const int* in_sizes, int n_in,
                              void* d_out, int out_size, void* d_ws,
                              size_t ws_size, hipStream_t stream) {
  const float* x    = (const float*)d_in[0];
  const float* Wq   = (const float*)d_in[1];
  const float* Wkv  = (const float*)d_in[2];
  const float* Wout = (const float*)d_in[3];
  const float* bout = (const float*)d_in[4];
  float* out = (float*)d_out;
  float* ws  = (float*)d_ws;

  float* C   = ws + OFF_C;
  float* T   = ws + OFF_T;
  float* att = ws + OFF_AT;
  float* WeT = ws + OFF_WE;
  float* Mt  = ws + OFF_MT;

  // C is accumulated with atomics; ws is poisoned before every call.
  hipMemsetAsync(C, 0, 131072 * sizeof(float), stream);

  k1_gram<<<dim3(64, 4, 2), 256, 0, stream>>>(x, C);
  k2_T<<<dim3(16, 16), 256, 0, stream>>>(Wq, C, T);
  k3_sim<<<dim3(16, 4), 256, 0, stream>>>(Wkv, T, att);
  k3b_softmax<<<dim3(16), 64, 0, stream>>>(att);
  k4_we<<<dim3(8, 8, 2), 256, 0, stream>>>(Wout, att, WeT);
  k5_M<<<dim3(64, 2), 256, 0, stream>>>(Wkv, WeT, Mt);
  k6_apply<<<dim3(256, 2), 256, 0, stream>>>(x, Mt, bout, out);
}

// Round 5
// 585.934 us; speedup vs baseline: 1.0929x; 1.0619x over previous
//
#include <hip/hip_runtime.h>
#include <cstdint>
#include <cstddef>

// Geometry: x (16,32,128,128) fp32 -> G=2 groups, F=256 features/group
// (= 8 batch-of-group * 32 ch), N=16384 positions, 8 heads/group, dim_head=64.
// Whole block collapses to: C[g]=F·F^T Gram; sim=Wq_h·C·Wk_h^T; attn=softmax;
// M[g] = (Wout·blockdiag_h(attn))·Wv; out = M[g]·f + bout.  All fp32.
constexpr int NP = 16384;

// ws layout (fp32 element offsets)
constexpr size_t OFF_C  = 0;        // C[2][256][256]       131072
constexpr size_t OFF_T  = 131072;   // T[16][64][256]       262144
constexpr size_t OFF_AT = 393216;   // sim/attn[16][64][64]  65536
constexpr size_t OFF_WE = 458752;   // WeT[2][512][256]     262144
constexpr size_t OFF_MT = 720896;   // Mt[2][256][256]      131072
// total 851968 floats = 3.25 MiB

// ---------------------------------------------------------------------------
// K1: C[g] += X * X^T over a K-chunk of 256 positions.  C symmetric -> only
// tiles (0,0),(0,128),(128,128); off-diag tile mirrored via transposed atomics.
// 128x128 C-tile per block, 4 waves, 8x8 micro-tile/lane, fp32 atomics out.
// amdgpu_waves_per_eu(1): R3/R4 showed the backend caps VGPR at 64 (its
// occupancy heuristic) and spills the 64-float acc -> 256 MiB scratch
// writeback, VALUBusy 8%.  min-waves=1 gives RA the full 512-VGPR budget.
__global__ __launch_bounds__(256) __attribute__((amdgpu_waves_per_eu(1)))
void k1_gram(const float* __restrict__ x, float* __restrict__ Cmat) {
  __shared__ float As[32 * 132];   // [kk][row0..127], pad 132 (16B-aligned)
  __shared__ float Bs[32 * 132];
  const int kc = blockIdx.x;            // 64 chunks of 256
  const int ty = blockIdx.y;            // 0:(0,0) 1:(0,128) 2:(128,128)
  const int g  = blockIdx.z;            // 2
  const int i0 = (ty == 2) ? 128 : 0;
  const int j0 = (ty == 0) ? 0 : 128;
  const float* __restrict__ Xg = x + (size_t)g * 256 * NP;
  const int tid  = threadIdx.x;
  const int lane = tid & 63;
  const int w    = tid >> 6;
  const int wy = (w >> 1) * 64;
  const int wx = (w & 1) * 64;
  const int ly = (lane >> 3) * 8;
  const int lx = (lane & 7) * 8;

  float acc[8][8];
#pragma unroll
  for (int e = 0; e < 8; ++e)
#pragma unroll
    for (int f = 0; f < 8; ++f) acc[e][f] = 0.f;

  const int k8   = (tid & 3) * 8;   // 4 chunks of 8 floats = 32 k per stage
  const int rowb = tid >> 2;        // 0..63
  const int k0 = kc * 256;

  for (int s = 0; s < 8; ++s) {
    const int ks = k0 + s * 32;
#pragma unroll
    for (int pass = 0; pass < 2; ++pass) {
      const int row = rowb + pass * 64;
      {
        const size_t e0 = (size_t)(i0 + row) * NP + ks + k8;
        float4 a = *(const float4*)(Xg + e0);
        float4 b = *(const float4*)(Xg + e0 + 4);
        As[(k8 + 0) * 132 + row] = a.x;
        As[(k8 + 1) * 132 + row] = a.y;
        As[(k8 + 2) * 132 + row] = a.z;
        As[(k8 + 3) * 132 + row] = a.w;
        As[(k8 + 4) * 132 + row] = b.x;
        As[(k8 + 5) * 132 + row] = b.y;
        As[(k8 + 6) * 132 + row] = b.z;
        As[(k8 + 7) * 132 + row] = b.w;
      }
      {
        const size_t e0 = (size_t)(j0 + row) * NP + ks + k8;
        float4 a = *(const float4*)(Xg + e0);
        float4 b = *(const float4*)(Xg + e0 + 4);
        Bs[(k8 + 0) * 132 + row] = a.x;
        Bs[(k8 + 1) * 132 + row] = a.y;
        Bs[(k8 + 2) * 132 + row] = a.z;
        Bs[(k8 + 3) * 132 + row] = a.w;
        Bs[(k8 + 4) * 132 + row] = b.x;
        Bs[(k8 + 5) * 132 + row] = b.y;
        Bs[(k8 + 6) * 132 + row] = b.z;
        Bs[(k8 + 7) * 132 + row] = b.w;
      }
    }
    __syncthreads();
#pragma unroll 4
    for (int kk = 0; kk < 32; ++kk) {
      const float* __restrict__ ar = &As[kk * 132 + wy + ly];
      const float* __restrict__ br = &Bs[kk * 132 + wx + lx];
      float4 a0 = *(const float4*)(ar);
      float4 a1 = *(const float4*)(ar + 4);
      float4 b0 = *(const float4*)(br);
      float4 b1 = *(const float4*)(br + 4);
      const float av[8] = {a0.x, a0.y, a0.z, a0.w, a1.x, a1.y, a1.z, a1.w};
      const float bv[8] = {b0.x, b0.y, b0.z, b0.w, b1.x, b1.y, b1.z, b1.w};
#pragma unroll
      for (int e = 0; e < 8; ++e)
#pragma unroll
        for (int f = 0; f < 8; ++f) acc[e][f] += av[e] * bv[f];
    }
    __syncthreads();
  }
  float* Cg = Cmat + (size_t)g * 65536;
#pragma unroll
  for (int e = 0; e < 8; ++e)
#pragma unroll
    for (int f = 0; f < 8; ++f)
      atomicAdd(&Cg[(i0 + wy + ly + e) * 256 + (j0 + wx + lx + f)],
                acc[e][f]);
  if (ty == 1) {  // mirror into the lower-triangular tile
#pragma unroll
    for (int e = 0; e < 8; ++e)
#pragma unroll
      for (int f = 0; f < 8; ++f)
        atomicAdd(&Cg[(j0 + wx + lx + f) * 256 + (i0 + wy + ly + e)],
                  acc[e][f]);
  }
}

// ---------------------------------------------------------------------------
// K2: T[bh][i][a] = sum_b Wq[hh*64+i][b] * C[g][b][a].  Lanes = a (coalesced),
// Wq rows via uniform scalar fp32 loads.
__global__ __launch_bounds__(256) void k2_T(const float* __restrict__ Wq,
                                            const float* __restrict__ Cmat,
                                            float* __restrict__ T) {
  const int bh = blockIdx.x;   // 16
  const int ic = blockIdx.y;   // 16 -> 4 rows each
  const int g = bh >> 3, hh = bh & 7;
  const int tid = threadIdx.x;
  const float* __restrict__ Cg = Cmat + (size_t)g * 65536;
  const int r0 = hh * 64 + ic * 4;
  float acc[4] = {0.f, 0.f, 0.f, 0.f};
  for (int b = 0; b < 256; ++b) {
    const float cv = Cg[(size_t)b * 256 + tid];
#pragma unroll
    for (int ii = 0; ii < 4; ++ii)
      acc[ii] += Wq[(size_t)(r0 + ii) * 256 + b] * cv;
  }
#pragma unroll
  for (int ii = 0; ii < 4; ++ii)
    T[((size_t)bh * 64 + ic * 4 + ii) * 256 + tid] = acc[ii];
}

// ---------------------------------------------------------------------------
// K3: sim[bh][i][j] = 0.125 * sum_a T[bh][i][a] * Wk[hh*64+j][a].
// Lanes = i; T staged in LDS with rotate-within-32 swizzle (row stride 256
// would put all 64 lanes on one bank); Wk rows via uniform scalar loads.
__global__ __launch_bounds__(256) void k3_sim(const float* __restrict__ Wkv,
                                              const float* __restrict__ T,
                                              float* __restrict__ simattn) {
  __shared__ float Ts[64 * 256];  // 64 KiB
  const int bh = blockIdx.x;  // 16
  const int jc = blockIdx.y;  // 4 -> 16 j each
  const int hh = bh & 7;
  const int tid = threadIdx.x;
  {
    const int f4i = tid & 63;   // 64 float4 chunks per 256-row
    const int rwb = tid >> 6;   // 0..3
    for (int pass = 0; pass < 16; ++pass) {
      const int row = rwb + pass * 4;
      float4 v = *(const float4*)(T + ((size_t)bh * 64 + row) * 256 + f4i * 4);
      const int a0 = f4i * 4;
      const float vv[4] = {v.x, v.y, v.z, v.w};
#pragma unroll
      for (int e = 0; e < 4; ++e) {
        const int a = a0 + e;
        Ts[row * 256 + (a & ~31) + ((a + row) & 31)] = vv[e];
      }
    }
  }
  __syncthreads();
  const int i  = tid & 63;
  const int jq = tid >> 6;
  const int jb = jc * 16 + jq * 4;
  float acc[4] = {0.f, 0.f, 0.f, 0.f};
  for (int a = 0; a < 256; ++a) {
    const float tv = Ts[i * 256 + (a & ~31) + ((a + i) & 31)];
#pragma unroll
    for (int jj = 0; jj < 4; ++jj)
      acc[jj] += Wkv[(size_t)(hh * 64 + jb + jj) * 256 + a] * tv;
  }
#pragma unroll
  for (int jj = 0; jj < 4; ++jj)
    simattn[((size_t)bh * 64 + i) * 64 + jb + jj] = acc[jj] * 0.125f;
}

// K3b: row softmax over j (in place), one lane per row.
__global__ __launch_bounds__(64) void k3b_softmax(float* __restrict__ simattn) {
  const int bh = blockIdx.x;
  const int i  = threadIdx.x;
  float* row = simattn + ((size_t)bh * 64 + i) * 64;
  float v[64];
  float m = -1e30f;
#pragma unroll
  for (int j = 0; j < 64; ++j) { v[j] = row[j]; m = fmaxf(m, v[j]); }
  float s = 0.f;
#pragma unroll
  for (int j = 0; j < 64; ++j) { v[j] = __expf(v[j] - m); s += v[j]; }
  const float inv = 1.0f / s;
#pragma unroll
  for (int j = 0; j < 64; ++j) row[j] = v[j] * inv;
}

// ---------------------------------------------------------------------------
// K4: WeT[g][hh*64+j][co] = sum_i Wout[co][hh*64+i] * attn[bh][i][j].
// Wout head-block staged in LDS, transposed access via rotate-by-co swizzle.
__global__ __launch_bounds__(256) void k4_we(const float* __restrict__ Wout,
                                             const float* __restrict__ attn,
                                             float* __restrict__ WeT) {
  __shared__ float WL[256 * 64];  // 64 KiB
  const int jc = blockIdx.x;  // 8 -> 8 j each
  const int hh = blockIdx.y;  // 8
  const int g  = blockIdx.z;  // 2
  const int bh = g * 8 + hh;
  const int tid = threadIdx.x;  // co lane
  {
    const int f4i = tid & 15;  // 16 float4 chunks per 64-col slab
    const int cb  = tid >> 4;  // 0..15
    for (int pass = 0; pass < 16; ++pass) {
      const int co = cb + pass * 16;
      float4 v = *(const float4*)(Wout + (size_t)co * 512 + hh * 64 + f4i * 4);
      const int a0 = f4i * 4;
      const float vv[4] = {v.x, v.y, v.z, v.w};
#pragma unroll
      for (int e = 0; e < 4; ++e)
        WL[co * 64 + ((a0 + e + co) & 63)] = vv[e];
    }
  }
  __syncthreads();
  const int jb = jc * 8;
  float acc[8] = {0.f, 0.f, 0.f, 0.f, 0.f, 0.f, 0.f, 0.f};
  for (int i = 0; i < 64; ++i) {
    const float wv = WL[tid * 64 + ((i + tid) & 63)];
#pragma unroll
    for (int je = 0; je < 8; ++je)
      acc[je] += attn[((size_t)bh * 64 + i) * 64 + jb + je] * wv;
  }
#pragma unroll
  for (int je = 0; je < 8; ++je)
    WeT[(size_t)g * 131072 + (size_t)(hh * 64 + jb + je) * 256 + tid] =
        acc[je];
}

// ---------------------------------------------------------------------------
// K5: Mt[g][b][co] = sum_o WeT[g][o][co] * Wv[o][b]; Wv = Wkv rows 512..1023.
__global__ __launch_bounds__(256) void k5_M(const float* __restrict__ Wkv,
                                            const float* __restrict__ WeT,
                                            float* __restrict__ Mt) {
  const int bc = blockIdx.x;  // 64 -> 4 b each
  const int g  = blockIdx.y;
  const int tid = threadIdx.x;  // co lane
  const int b0 = bc * 4;
  const float* __restrict__ Weg = WeT + (size_t)g * 131072;
  float acc[4] = {0.f, 0.f, 0.f, 0.f};
  for (int o = 0; o < 512; ++o) {
    const float wv = Weg[(size_t)o * 256 + tid];
    const float* __restrict__ vr = Wkv + (size_t)(512 + o) * 256 + b0;
    acc[0] += vr[0] * wv;
    acc[1] += vr[1] * wv;
    acc[2] += vr[2] * wv;
    acc[3] += vr[3] * wv;
  }
#pragma unroll
  for (int be = 0; be < 4; ++be)
    Mt[(size_t)g * 65536 + (size_t)(b0 + be) * 256 + tid] = acc[be];
}

// ---------------------------------------------------------------------------
// K6: out[co][p] = bout[co] + sum_f Mt[g][f][co] * F[g][f][p], per group.
// Standard 128x128-tile GEMM: both operands are k-major in memory (Mt rows
// contiguous in co, x rows contiguous in p) -> pure float4 LDS staging.
// 8x8 micro-tile/lane, 4 waves; same spill-proof skeleton as k1.
__global__ __launch_bounds__(256) __attribute__((amdgpu_waves_per_eu(1)))
void k6_apply(const float* __restrict__ x, const float* __restrict__ Mt,
              const float* __restrict__ bout, float* __restrict__ out) {
  __shared__ float As[32 * 132];   // [kk][co' 0..127]
  __shared__ float Bs[32 * 132];   // [kk][p'  0..127]
  const int pc = blockIdx.x;  // 128 p-tiles
  const int oy = blockIdx.y;  // 2 co-tiles
  const int g  = blockIdx.z;  // 2
  const int p0 = pc * 128;
  const int o0 = oy * 128;
  const float* __restrict__ Xg = x + (size_t)g * 256 * NP;
  const float* __restrict__ Mg = Mt + (size_t)g * 65536;
  const int tid  = threadIdx.x;
  const int lane = tid & 63;
  const int w    = tid >> 6;
  const int wy = (w >> 1) * 64;
  const int wx = (w & 1) * 64;
  const int ly = (lane >> 3) * 8;
  const int lx = (lane & 7) * 8;

  float acc[8][8];
#pragma unroll
  for (int e = 0; e < 8; ++e)
#pragma unroll
    for (int f = 0; f < 8; ++f) acc[e][f] = 0.f;

  const int c4 = (tid & 31) * 4;  // 32 float4 chunks per 128-wide row
  const int kb = tid >> 5;        // 0..7

  for (int s = 0; s < 8; ++s) {
#pragma unroll
    for (int r = 0; r < 4; ++r) {
      const int kk = kb + r * 8;
      const int f  = s * 32 + kk;
      *(float4*)&As[kk * 132 + c4] =
          *(const float4*)(Mg + (size_t)f * 256 + o0 + c4);
      *(float4*)&Bs[kk * 132 + c4] =
          *(const float4*)(Xg + (size_t)f * NP + p0 + c4);
    }
    __syncthreads();
#pragma unroll 4
    for (int kk = 0; kk < 32; ++kk) {
      const float* __restrict__ ar = &As[kk * 132 + wy + ly];
      const float* __restrict__ br = &Bs[kk * 132 + wx + lx];
      float4 a0 = *(const float4*)(ar);
      float4 a1 = *(const float4*)(ar + 4);
      float4 b0 = *(const float4*)(br);
      float4 b1 = *(const float4*)(br + 4);
      const float av[8] = {a0.x, a0.y, a0.z, a0.w, a1.x, a1.y, a1.z, a1.w};
      const float bv[8] = {b0.x, b0.y, b0.z, b0.w, b1.x, b1.y, b1.z, b1.w};
#pragma unroll
      for (int e = 0; e < 8; ++e)
#pragma unroll
        for (int f = 0; f < 8; ++f) acc[e][f] += av[e] * bv[f];
    }
    __syncthreads();
  }
#pragma unroll
  for (int e = 0; e < 8; ++e) {
    const int co = o0 + wy + ly + e;
    const float bo = bout[co];
    float* __restrict__ orow =
        out + ((size_t)(g * 256 + co)) * NP + p0 + wx + lx;
    float4 s0 = {acc[e][0] + bo, acc[e][1] + bo, acc[e][2] + bo,
                 acc[e][3] + bo};
    float4 s1 = {acc[e][4] + bo, acc[e][5] + bo, acc[e][6] + bo,
                 acc[e][7] + bo};
    *(float4*)(orow)     = s0;
    *(float4*)(orow + 4) = s1;
  }
}

// ---------------------------------------------------------------------------
extern "C" void kernel_launch(void* const* d_in, const int* in_sizes, int n_in,
                              void* d_out, int out_size, void* d_ws,
                              size_t ws_size, hipStream_t stream) {
  const float* x    = (const float*)d_in[0];
  const float* Wq   = (const float*)d_in[1];
  const float* Wkv  = (const float*)d_in[2];
  const float* Wout = (const float*)d_in[3];
  const float* bout = (const float*)d_in[4];
  float* out = (float*)d_out;
  float* ws  = (float*)d_ws;

  float* C   = ws + OFF_C;
  float* T   = ws + OFF_T;
  float* att = ws + OFF_AT;
  float* WeT = ws + OFF_WE;
  float* Mt  = ws + OFF_MT;

  // C is accumulated with atomics; ws is poisoned before every call.
  hipMemsetAsync(C, 0, 131072 * sizeof(float), stream);

  k1_gram<<<dim3(64, 3, 2), 256, 0, stream>>>(x, C);
  k2_T<<<dim3(16, 16), 256, 0, stream>>>(Wq, C, T);
  k3_sim<<<dim3(16, 4), 256, 0, stream>>>(Wkv, T, att);
  k3b_softmax<<<dim3(16), 64, 0, stream>>>(att);
  k4_we<<<dim3(8, 8, 2), 256, 0, stream>>>(Wout, att, WeT);
  k5_M<<<dim3(64, 2), 256, 0, stream>>>(Wkv, WeT, Mt);
  k6_apply<<<dim3(128, 2, 2), 256, 0, stream>>>(x, Mt, bout, out);
}

// Round 6
// 266.593 us; speedup vs baseline: 2.4021x; 2.1979x over previous
//
#include <hip/hip_runtime.h>
#include <cstdint>
#include <cstddef>

// Geometry: x (16,32,128,128) fp32 -> G=2 groups, F=256 features/group
// (= 8 batch-of-group * 32 ch), N=16384 positions, 8 heads/group, dim_head=64.
// Whole block collapses to: C[g]=F·F^T Gram; sim=Wq_h·C·Wk_h^T; attn=softmax;
// M[g] = (Wout·blockdiag_h(attn))·Wv; out = M[g]·f + bout.  All fp32.
constexpr int NP = 16384;

// ws layout (fp32 element offsets)
constexpr size_t OFF_C     = 0;        // C[2][256][256]       131072
constexpr size_t OFF_T     = 131072;   // T[16][64][256]       262144
constexpr size_t OFF_AT    = 393216;   // sim/attn[16][64][64]  65536
constexpr size_t OFF_WE    = 458752;   // WeT[2][512][256]     262144
constexpr size_t OFF_MT    = 720896;   // Mt[2][256][256]      131072
constexpr size_t OFF_CP    = 851968;   // Cpart[2][3][64][128*128]  6291456
constexpr size_t WS_NEEDED = (OFF_CP + 6291456) * 4;  // bytes (~36.6 MB)

// ---------------------------------------------------------------------------
// K1: Gram partials.  C symmetric -> tiles ty=0:(0,0) 1:(0,128) 2:(128,128).
// Each block computes a 128x128 partial over a 256-position K-chunk and
// writes it to its PRIVATE slab (no atomics).  R3-R5 post-mortem: the old
// atomicAdd epilogue was the whole bottleneck - 8.39M device atomics x 32B
// TCC granule = 262144 KB WRITE_SIZE at ~655 GB/s = ~410 us, constant across
// rounds regardless of compute changes.
__global__ __launch_bounds__(256)
void k1_gram(const float* __restrict__ x, float* __restrict__ Cpart) {
  __shared__ float As[32 * 132];   // [kk][row0..127], pad 132 (16B-aligned)
  __shared__ float Bs[32 * 132];
  const int kc = blockIdx.x;            // 64 chunks of 256
  const int ty = blockIdx.y;            // 0:(0,0) 1:(0,128) 2:(128,128)
  const int g  = blockIdx.z;            // 2
  const int i0 = (ty == 2) ? 128 : 0;
  const int j0 = (ty == 0) ? 0 : 128;
  const float* __restrict__ Xg = x + (size_t)g * 256 * NP;
  const int tid  = threadIdx.x;
  const int lane = tid & 63;
  const int w    = tid >> 6;
  const int wy = (w >> 1) * 64;
  const int wx = (w & 1) * 64;
  const int ly = (lane >> 3) * 8;
  const int lx = (lane & 7) * 8;

  float acc[8][8];
#pragma unroll
  for (int e = 0; e < 8; ++e)
#pragma unroll
    for (int f = 0; f < 8; ++f) acc[e][f] = 0.f;

  const int k8   = (tid & 3) * 8;   // 4 chunks of 8 floats = 32 k per stage
  const int rowb = tid >> 2;        // 0..63
  const int k0 = kc * 256;

  for (int s = 0; s < 8; ++s) {
    const int ks = k0 + s * 32;
#pragma unroll
    for (int pass = 0; pass < 2; ++pass) {
      const int row = rowb + pass * 64;
      {
        const size_t e0 = (size_t)(i0 + row) * NP + ks + k8;
        float4 a = *(const float4*)(Xg + e0);
        float4 b = *(const float4*)(Xg + e0 + 4);
        As[(k8 + 0) * 132 + row] = a.x;
        As[(k8 + 1) * 132 + row] = a.y;
        As[(k8 + 2) * 132 + row] = a.z;
        As[(k8 + 3) * 132 + row] = a.w;
        As[(k8 + 4) * 132 + row] = b.x;
        As[(k8 + 5) * 132 + row] = b.y;
        As[(k8 + 6) * 132 + row] = b.z;
        As[(k8 + 7) * 132 + row] = b.w;
      }
      {
        const size_t e0 = (size_t)(j0 + row) * NP + ks + k8;
        float4 a = *(const float4*)(Xg + e0);
        float4 b = *(const float4*)(Xg + e0 + 4);
        Bs[(k8 + 0) * 132 + row] = a.x;
        Bs[(k8 + 1) * 132 + row] = a.y;
        Bs[(k8 + 2) * 132 + row] = a.z;
        Bs[(k8 + 3) * 132 + row] = a.w;
        Bs[(k8 + 4) * 132 + row] = b.x;
        Bs[(k8 + 5) * 132 + row] = b.y;
        Bs[(k8 + 6) * 132 + row] = b.z;
        Bs[(k8 + 7) * 132 + row] = b.w;
      }
    }
    __syncthreads();
#pragma unroll 4
    for (int kk = 0; kk < 32; ++kk) {
      const float* __restrict__ ar = &As[kk * 132 + wy + ly];
      const float* __restrict__ br = &Bs[kk * 132 + wx + lx];
      float4 a0 = *(const float4*)(ar);
      float4 a1 = *(const float4*)(ar + 4);
      float4 b0 = *(const float4*)(br);
      float4 b1 = *(const float4*)(br + 4);
      const float av[8] = {a0.x, a0.y, a0.z, a0.w, a1.x, a1.y, a1.z, a1.w};
      const float bv[8] = {b0.x, b0.y, b0.z, b0.w, b1.x, b1.y, b1.z, b1.w};
#pragma unroll
      for (int e = 0; e < 8; ++e)
#pragma unroll
        for (int f = 0; f < 8; ++f) acc[e][f] += av[e] * bv[f];
    }
    __syncthreads();
  }
  // Private partial slab: coalesced float4 stores, no atomics.
  float* __restrict__ P =
      Cpart + (((size_t)g * 3 + ty) * 64 + kc) * 16384;
#pragma unroll
  for (int e = 0; e < 8; ++e) {
    float* pr = P + (size_t)(wy + ly + e) * 128 + wx + lx;
    float4 s0 = {acc[e][0], acc[e][1], acc[e][2], acc[e][3]};
    float4 s1 = {acc[e][4], acc[e][5], acc[e][6], acc[e][7]};
    *(float4*)(pr)     = s0;
    *(float4*)(pr + 4) = s1;
  }
}

// K1b: reduce the 64 K-chunk partials per tile into C; mirror ty==1.
__global__ __launch_bounds__(256)
void k1b_reduce(const float* __restrict__ Cpart, float* __restrict__ Cmat) {
  const int sl = blockIdx.x;  // 64 slices of 256 elements
  const int ty = blockIdx.y;  // 3
  const int g  = blockIdx.z;  // 2
  const int ele = sl * 256 + threadIdx.x;      // 0..16383 within tile
  const float* __restrict__ P =
      Cpart + (((size_t)g * 3 + ty) * 64) * 16384 + ele;
  float v = 0.f;
#pragma unroll 8
  for (int kc = 0; kc < 64; ++kc) v += P[(size_t)kc * 16384];
  const int i0 = (ty == 2) ? 128 : 0;
  const int j0 = (ty == 0) ? 0 : 128;
  const int i = ele >> 7, j = ele & 127;
  float* Cg = Cmat + (size_t)g * 65536;
  Cg[(size_t)(i0 + i) * 256 + (j0 + j)] = v;
  if (ty == 1) Cg[(size_t)(j0 + j) * 256 + (i0 + i)] = v;
}

// Fallback (ws too small): old atomic version.
__global__ __launch_bounds__(256)
void k1_gram_atomic(const float* __restrict__ x, float* __restrict__ Cmat) {
  __shared__ float As[32 * 132];
  __shared__ float Bs[32 * 132];
  const int kc = blockIdx.x, ty = blockIdx.y, g = blockIdx.z;
  const int i0 = (ty == 2) ? 128 : 0;
  const int j0 = (ty == 0) ? 0 : 128;
  const float* __restrict__ Xg = x + (size_t)g * 256 * NP;
  const int tid = threadIdx.x, lane = tid & 63, w = tid >> 6;
  const int wy = (w >> 1) * 64, wx = (w & 1) * 64;
  const int ly = (lane >> 3) * 8, lx = (lane & 7) * 8;
  float acc[8][8];
#pragma unroll
  for (int e = 0; e < 8; ++e)
#pragma unroll
    for (int f = 0; f < 8; ++f) acc[e][f] = 0.f;
  const int k8 = (tid & 3) * 8, rowb = tid >> 2, k0 = kc * 256;
  for (int s = 0; s < 8; ++s) {
    const int ks = k0 + s * 32;
#pragma unroll
    for (int pass = 0; pass < 2; ++pass) {
      const int row = rowb + pass * 64;
      const size_t ea = (size_t)(i0 + row) * NP + ks + k8;
      float4 a = *(const float4*)(Xg + ea);
      float4 b = *(const float4*)(Xg + ea + 4);
      As[(k8+0)*132+row]=a.x; As[(k8+1)*132+row]=a.y;
      As[(k8+2)*132+row]=a.z; As[(k8+3)*132+row]=a.w;
      As[(k8+4)*132+row]=b.x; As[(k8+5)*132+row]=b.y;
      As[(k8+6)*132+row]=b.z; As[(k8+7)*132+row]=b.w;
      const size_t eb = (size_t)(j0 + row) * NP + ks + k8;
      a = *(const float4*)(Xg + eb);
      b = *(const float4*)(Xg + eb + 4);
      Bs[(k8+0)*132+row]=a.x; Bs[(k8+1)*132+row]=a.y;
      Bs[(k8+2)*132+row]=a.z; Bs[(k8+3)*132+row]=a.w;
      Bs[(k8+4)*132+row]=b.x; Bs[(k8+5)*132+row]=b.y;
      Bs[(k8+6)*132+row]=b.z; Bs[(k8+7)*132+row]=b.w;
    }
    __syncthreads();
#pragma unroll 4
    for (int kk = 0; kk < 32; ++kk) {
      const float* ar = &As[kk * 132 + wy + ly];
      const float* br = &Bs[kk * 132 + wx + lx];
      float4 a0 = *(const float4*)(ar), a1 = *(const float4*)(ar + 4);
      float4 b0 = *(const float4*)(br), b1 = *(const float4*)(br + 4);
      const float av[8] = {a0.x,a0.y,a0.z,a0.w,a1.x,a1.y,a1.z,a1.w};
      const float bv[8] = {b0.x,b0.y,b0.z,b0.w,b1.x,b1.y,b1.z,b1.w};
#pragma unroll
      for (int e = 0; e < 8; ++e)
#pragma unroll
        for (int f = 0; f < 8; ++f) acc[e][f] += av[e] * bv[f];
    }
    __syncthreads();
  }
  float* Cg = Cmat + (size_t)g * 65536;
#pragma unroll
  for (int e = 0; e < 8; ++e)
#pragma unroll
    for (int f = 0; f < 8; ++f) {
      atomicAdd(&Cg[(i0+wy+ly+e)*256 + (j0+wx+lx+f)], acc[e][f]);
      if (ty == 1)
        atomicAdd(&Cg[(j0+wx+lx+f)*256 + (i0+wy+ly+e)], acc[e][f]);
    }
}

// ---------------------------------------------------------------------------
// K2: T[bh][i][a] = sum_b Wq[hh*64+i][b] * C[g][b][a].  Lanes = a (coalesced),
// Wq rows via uniform scalar fp32 loads.
__global__ __launch_bounds__(256) void k2_T(const float* __restrict__ Wq,
                                            const float* __restrict__ Cmat,
                                            float* __restrict__ T) {
  const int bh = blockIdx.x;   // 16
  const int ic = blockIdx.y;   // 16 -> 4 rows each
  const int g = bh >> 3, hh = bh & 7;
  const int tid = threadIdx.x;
  const float* __restrict__ Cg = Cmat + (size_t)g * 65536;
  const int r0 = hh * 64 + ic * 4;
  float acc[4] = {0.f, 0.f, 0.f, 0.f};
  for (int b = 0; b < 256; ++b) {
    const float cv = Cg[(size_t)b * 256 + tid];
#pragma unroll
    for (int ii = 0; ii < 4; ++ii)
      acc[ii] += Wq[(size_t)(r0 + ii) * 256 + b] * cv;
  }
#pragma unroll
  for (int ii = 0; ii < 4; ++ii)
    T[((size_t)bh * 64 + ic * 4 + ii) * 256 + tid] = acc[ii];
}

// ---------------------------------------------------------------------------
// K3: sim[bh][i][j] = 0.125 * sum_a T[bh][i][a] * Wk[hh*64+j][a].
// Lanes = i; T staged in LDS with rotate-within-32 swizzle (row stride 256
// would put all 64 lanes on one bank); Wk rows via uniform scalar loads.
__global__ __launch_bounds__(256) void k3_sim(const float* __restrict__ Wkv,
                                              const float* __restrict__ T,
                                              float* __restrict__ simattn) {
  __shared__ float Ts[64 * 256];  // 64 KiB
  const int bh = blockIdx.x;  // 16
  const int jc = blockIdx.y;  // 4 -> 16 j each
  const int hh = bh & 7;
  const int tid = threadIdx.x;
  {
    const int f4i = tid & 63;   // 64 float4 chunks per 256-row
    const int rwb = tid >> 6;   // 0..3
    for (int pass = 0; pass < 16; ++pass) {
      const int row = rwb + pass * 4;
      float4 v = *(const float4*)(T + ((size_t)bh * 64 + row) * 256 + f4i * 4);
      const int a0 = f4i * 4;
      const float vv[4] = {v.x, v.y, v.z, v.w};
#pragma unroll
      for (int e = 0; e < 4; ++e) {
        const int a = a0 + e;
        Ts[row * 256 + (a & ~31) + ((a + row) & 31)] = vv[e];
      }
    }
  }
  __syncthreads();
  const int i  = tid & 63;
  const int jq = tid >> 6;
  const int jb = jc * 16 + jq * 4;
  float acc[4] = {0.f, 0.f, 0.f, 0.f};
  for (int a = 0; a < 256; ++a) {
    const float tv = Ts[i * 256 + (a & ~31) + ((a + i) & 31)];
#pragma unroll
    for (int jj = 0; jj < 4; ++jj)
      acc[jj] += Wkv[(size_t)(hh * 64 + jb + jj) * 256 + a] * tv;
  }
#pragma unroll
  for (int jj = 0; jj < 4; ++jj)
    simattn[((size_t)bh * 64 + i) * 64 + jb + jj] = acc[jj] * 0.125f;
}

// K3b: row softmax over j (in place), one lane per row.
__global__ __launch_bounds__(64) void k3b_softmax(float* __restrict__ simattn) {
  const int bh = blockIdx.x;
  const int i  = threadIdx.x;
  float* row = simattn + ((size_t)bh * 64 + i) * 64;
  float v[64];
  float m = -1e30f;
#pragma unroll
  for (int j = 0; j < 64; ++j) { v[j] = row[j]; m = fmaxf(m, v[j]); }
  float s = 0.f;
#pragma unroll
  for (int j = 0; j < 64; ++j) { v[j] = __expf(v[j] - m); s += v[j]; }
  const float inv = 1.0f / s;
#pragma unroll
  for (int j = 0; j < 64; ++j) row[j] = v[j] * inv;
}

// ---------------------------------------------------------------------------
// K4: WeT[g][hh*64+j][co] = sum_i Wout[co][hh*64+i] * attn[bh][i][j].
// Wout head-block staged in LDS, transposed access via rotate-by-co swizzle.
__global__ __launch_bounds__(256) void k4_we(const float* __restrict__ Wout,
                                             const float* __restrict__ attn,
                                             float* __restrict__ WeT) {
  __shared__ float WL[256 * 64];  // 64 KiB
  const int jc = blockIdx.x;  // 8 -> 8 j each
  const int hh = blockIdx.y;  // 8
  const int g  = blockIdx.z;  // 2
  const int bh = g * 8 + hh;
  const int tid = threadIdx.x;  // co lane
  {
    const int f4i = tid & 15;  // 16 float4 chunks per 64-col slab
    const int cb  = tid >> 4;  // 0..15
    for (int pass = 0; pass < 16; ++pass) {
      const int co = cb + pass * 16;
      float4 v = *(const float4*)(Wout + (size_t)co * 512 + hh * 64 + f4i * 4);
      const int a0 = f4i * 4;
      const float vv[4] = {v.x, v.y, v.z, v.w};
#pragma unroll
      for (int e = 0; e < 4; ++e)
        WL[co * 64 + ((a0 + e + co) & 63)] = vv[e];
    }
  }
  __syncthreads();
  const int jb = jc * 8;
  float acc[8] = {0.f, 0.f, 0.f, 0.f, 0.f, 0.f, 0.f, 0.f};
  for (int i = 0; i < 64; ++i) {
    const float wv = WL[tid * 64 + ((i + tid) & 63)];
#pragma unroll
    for (int je = 0; je < 8; ++je)
      acc[je] += attn[((size_t)bh * 64 + i) * 64 + jb + je] * wv;
  }
#pragma unroll
  for (int je = 0; je < 8; ++je)
    WeT[(size_t)g * 131072 + (size_t)(hh * 64 + jb + je) * 256 + tid] =
        acc[je];
}

// ---------------------------------------------------------------------------
// K5: Mt[g][b][co] = sum_o WeT[g][o][co] * Wv[o][b]; Wv = Wkv rows 512..1023.
__global__ __launch_bounds__(256) void k5_M(const float* __restrict__ Wkv,
                                            const float* __restrict__ WeT,
                                            float* __restrict__ Mt) {
  const int bc = blockIdx.x;  // 64 -> 4 b each
  const int g  = blockIdx.y;
  const int tid = threadIdx.x;  // co lane
  const int b0 = bc * 4;
  const float* __restrict__ Weg = WeT + (size_t)g * 131072;
  float acc[4] = {0.f, 0.f, 0.f, 0.f};
  for (int o = 0; o < 512; ++o) {
    const float wv = Weg[(size_t)o * 256 + tid];
    const float* __restrict__ vr = Wkv + (size_t)(512 + o) * 256 + b0;
    acc[0] += vr[0] * wv;
    acc[1] += vr[1] * wv;
    acc[2] += vr[2] * wv;
    acc[3] += vr[3] * wv;
  }
#pragma unroll
  for (int be = 0; be < 4; ++be)
    Mt[(size_t)g * 65536 + (size_t)(b0 + be) * 256 + tid] = acc[be];
}

// ---------------------------------------------------------------------------
// K6: out[co][p] = bout[co] + sum_f Mt[g][f][co] * F[g][f][p], per group.
// Standard 128x128-tile GEMM: both operands k-major -> float4 LDS staging.
__global__ __launch_bounds__(256)
void k6_apply(const float* __restrict__ x, const float* __restrict__ Mt,
              const float* __restrict__ bout, float* __restrict__ out) {
  __shared__ float As[32 * 132];   // [kk][co' 0..127]
  __shared__ float Bs[32 * 132];   // [kk][p'  0..127]
  const int pc = blockIdx.x;  // 128 p-tiles
  const int oy = blockIdx.y;  // 2 co-tiles
  const int g  = blockIdx.z;  // 2
  const int p0 = pc * 128;
  const int o0 = oy * 128;
  const float* __restrict__ Xg = x + (size_t)g * 256 * NP;
  const float* __restrict__ Mg = Mt + (size_t)g * 65536;
  const int tid  = threadIdx.x;
  const int lane = tid & 63;
  const int w    = tid >> 6;
  const int wy = (w >> 1) * 64;
  const int wx = (w & 1) * 64;
  const int ly = (lane >> 3) * 8;
  const int lx = (lane & 7) * 8;

  float acc[8][8];
#pragma unroll
  for (int e = 0; e < 8; ++e)
#pragma unroll
    for (int f = 0; f < 8; ++f) acc[e][f] = 0.f;

  const int c4 = (tid & 31) * 4;  // 32 float4 chunks per 128-wide row
  const int kb = tid >> 5;        // 0..7

  for (int s = 0; s < 8; ++s) {
#pragma unroll
    for (int r = 0; r < 4; ++r) {
      const int kk = kb + r * 8;
      const int f  = s * 32 + kk;
      *(float4*)&As[kk * 132 + c4] =
          *(const float4*)(Mg + (size_t)f * 256 + o0 + c4);
      *(float4*)&Bs[kk * 132 + c4] =
          *(const float4*)(Xg + (size_t)f * NP + p0 + c4);
    }
    __syncthreads();
#pragma unroll 4
    for (int kk = 0; kk < 32; ++kk) {
      const float* __restrict__ ar = &As[kk * 132 + wy + ly];
      const float* __restrict__ br = &Bs[kk * 132 + wx + lx];
      float4 a0 = *(const float4*)(ar);
      float4 a1 = *(const float4*)(ar + 4);
      float4 b0 = *(const float4*)(br);
      float4 b1 = *(const float4*)(br + 4);
      const float av[8] = {a0.x, a0.y, a0.z, a0.w, a1.x, a1.y, a1.z, a1.w};
      const float bv[8] = {b0.x, b0.y, b0.z, b0.w, b1.x, b1.y, b1.z, b1.w};
#pragma unroll
      for (int e = 0; e < 8; ++e)
#pragma unroll
        for (int f = 0; f < 8; ++f) acc[e][f] += av[e] * bv[f];
    }
    __syncthreads();
  }
#pragma unroll
  for (int e = 0; e < 8; ++e) {
    const int co = o0 + wy + ly + e;
    const float bo = bout[co];
    float* __restrict__ orow =
        out + ((size_t)(g * 256 + co)) * NP + p0 + wx + lx;
    float4 s0 = {acc[e][0] + bo, acc[e][1] + bo, acc[e][2] + bo,
                 acc[e][3] + bo};
    float4 s1 = {acc[e][4] + bo, acc[e][5] + bo, acc[e][6] + bo,
                 acc[e][7] + bo};
    *(float4*)(orow)     = s0;
    *(float4*)(orow + 4) = s1;
  }
}

// ---------------------------------------------------------------------------
extern "C" void kernel_launch(void* const* d_in, const int* in_sizes, int n_in,
                              void* d_out, int out_size, void* d_ws,
                              size_t ws_size, hipStream_t stream) {
  const float* x    = (const float*)d_in[0];
  const float* Wq   = (const float*)d_in[1];
  const float* Wkv  = (const float*)d_in[2];
  const float* Wout = (const float*)d_in[3];
  const float* bout = (const float*)d_in[4];
  float* out = (float*)d_out;
  float* ws  = (float*)d_ws;

  float* C     = ws + OFF_C;
  float* T     = ws + OFF_T;
  float* att   = ws + OFF_AT;
  float* WeT   = ws + OFF_WE;
  float* Mt    = ws + OFF_MT;
  float* Cpart = ws + OFF_CP;

  if (ws_size >= WS_NEEDED) {
    k1_gram<<<dim3(64, 3, 2), 256, 0, stream>>>(x, Cpart);
    k1b_reduce<<<dim3(64, 3, 2), 256, 0, stream>>>(Cpart, C);
  } else {
    hipMemsetAsync(C, 0, 131072 * sizeof(float), stream);
    k1_gram_atomic<<<dim3(64, 3, 2), 256, 0, stream>>>(x, C);
  }
  k2_T<<<dim3(16, 16), 256, 0, stream>>>(Wq, C, T);
  k3_sim<<<dim3(16, 4), 256, 0, stream>>>(Wkv, T, att);
  k3b_softmax<<<dim3(16), 64, 0, stream>>>(att);
  k4_we<<<dim3(8, 8, 2), 256, 0, stream>>>(Wout, att, WeT);
  k5_M<<<dim3(64, 2), 256, 0, stream>>>(Wkv, WeT, Mt);
  k6_apply<<<dim3(128, 2, 2), 256, 0, stream>>>(x, Mt, bout, out);
}

// Round 7
// 227.371 us; speedup vs baseline: 2.8165x; 1.1725x over previous
//
#include <hip/hip_runtime.h>
#include <cstdint>
#include <cstddef>

using u16 = unsigned short;
using u32 = unsigned int;

typedef __attribute__((ext_vector_type(8))) short bf16x8;   // 8 bf16 = 4 VGPRs
typedef __attribute__((ext_vector_type(16))) float f32x16;  // MFMA 32x32 acc

__device__ __forceinline__ u16 f2bf(float f) {  // round-to-nearest-even
  union { float f; u32 i; } x; x.f = f;
  u32 r = (x.i + 0x7FFFu + ((x.i >> 16) & 1u)) >> 16;
  return (u16)r;
}
__device__ __forceinline__ bf16x8 ldbf16x8(const u16* p) {
  union { uint4 u; bf16x8 v; } t;
  t.u = *(const uint4*)p;
  return t.v;
}

// Geometry: x (16,32,128,128) fp32 -> G=2 groups, F=256 features/group,
// N=16384 positions, 8 heads/group, dim_head=64.  Collapse:
// C[g]=F·F^T Gram; sim=Wq_h·C·Wk_h^T; attn=softmax; M=(Wout·bd(attn))·Wv;
// out = M·f + bout.
constexpr int NP = 16384;

// ws layout (fp32 element offsets)
constexpr size_t OFF_C   = 0;        // C[2][256][256]        131072
constexpr size_t OFF_T   = 131072;   // T[16][64][256]        262144
constexpr size_t OFF_AT  = 393216;   // sim/attn[16][64][64]   65536
constexpr size_t OFF_WE  = 458752;   // WeT[2][512][256]      262144
constexpr size_t OFF_MT  = 720896;   // Mt fp32 [2][256][256] 131072
constexpr size_t OFF_MA  = 851968;   // M_A bf16 [2][256co][256f] (65536 fl)
constexpr size_t OFF_XB  = 917504;   // Xb  bf16 [2][256f][16384p] (4194304 fl)
constexpr size_t OFF_XBT = 5111808;  // XbT bf16 [2][16384p][256f] (4194304 fl)
constexpr size_t OFF_CP1 = 9306112;  // Cpart1 [2][16tp][16kc][4096] (2097152 fl)
constexpr size_t NEED1   = (OFF_CP1 + 2097152) * 4;  // 45,613,056 B
constexpr size_t OFF_CP2 = 851968;   // fp32-fallback partials (6291456 fl)
constexpr size_t NEED2   = (OFF_CP2 + 6291456) * 4;  // 28,573,696 B

// ---------------------------------------------------------------------------
// K0: x fp32 -> Xb bf16 (same layout) + XbT bf16 (transposed, for k6's A).
// 256f x 64p slab per block; LDS transpose with pad-65 rows.
__global__ __launch_bounds__(256)
void k0_cvt(const float* __restrict__ x, u16* __restrict__ Xb,
            u16* __restrict__ XbT) {
  __shared__ float Fs[256 * 65];
  const int pc = blockIdx.x;   // 256 chunks of 64 positions
  const int g  = blockIdx.y;
  const int p0 = pc * 64;
  const float* __restrict__ Xg = x + (size_t)g * 256 * NP;
  u16* __restrict__ Xbg  = Xb  + (size_t)g * 256 * NP;
  u16* __restrict__ XbTg = XbT + (size_t)g * NP * 256;
  const int tid = threadIdx.x;
  const int f8i = tid & 7, rb = tid >> 3;
  for (int pass = 0; pass < 8; ++pass) {
    const int row = rb + pass * 32;
    const size_t e0 = (size_t)row * NP + p0 + f8i * 8;
    float4 a = *(const float4*)(Xg + e0);
    float4 b = *(const float4*)(Xg + e0 + 4);
    const float v[8] = {a.x, a.y, a.z, a.w, b.x, b.y, b.z, b.w};
    uint4 s;
    s.x = (u32)f2bf(v[0]) | ((u32)f2bf(v[1]) << 16);
    s.y = (u32)f2bf(v[2]) | ((u32)f2bf(v[3]) << 16);
    s.z = (u32)f2bf(v[4]) | ((u32)f2bf(v[5]) << 16);
    s.w = (u32)f2bf(v[6]) | ((u32)f2bf(v[7]) << 16);
    *(uint4*)(Xbg + e0) = s;
    float* d = &Fs[row * 65 + f8i * 8];
#pragma unroll
    for (int e = 0; e < 8; ++e) d[e] = v[e];
  }
  __syncthreads();
  const int p = tid & 63, grp = tid >> 6;
  u16* dst = XbTg + (size_t)(p0 + p) * 256 + grp * 64;
  for (int c = 0; c < 4; ++c) {
    u32 w[8];
#pragma unroll
    for (int q = 0; q < 8; ++q) {
      const int f = grp * 64 + c * 16 + q * 2;
      u32 lo = f2bf(Fs[f * 65 + p]);
      u32 hi = f2bf(Fs[(f + 1) * 65 + p]);
      w[q] = lo | (hi << 16);
    }
    uint4 s0 = {w[0], w[1], w[2], w[3]};
    uint4 s1 = {w[4], w[5], w[6], w[7]};
    *(uint4*)(dst + c * 16)     = s0;
    *(uint4*)(dst + c * 16 + 8) = s1;
  }
}

// ---------------------------------------------------------------------------
// K1 (MFMA): Cpart[g][tp][kc] = 64x64 tile of Xb·Xb^T over a 1024-pos K-chunk.
// 4 waves = 2x2 quadrants of 32x32; v_mfma_f32_32x32x16_bf16, fp32 acc.
// Layouts (learn_hip-verified): A[m=l&31][k=(l>>5)*8+j]; B mirrored;
// C/D row=(r&3)+8*(r>>2)+4*(l>>5), col=l&31.
__global__ __launch_bounds__(256)
void k1_mfma(const u16* __restrict__ Xb, float* __restrict__ Cpart) {
  const int kc = blockIdx.x;   // 16 chunks of 1024 positions
  const int tp = blockIdx.y;   // 16 tile positions (4x4 of 64x64)
  const int g  = blockIdx.z;
  const int ti = tp >> 2, tj = tp & 3;
  const int tid = threadIdx.x;
  const int w = tid >> 6, half = (tid >> 5) & 1, lc = tid & 31;
  const int qi = w >> 1, qj = w & 1;
  const u16* __restrict__ Xg = Xb + (size_t)g * 256 * NP;
  const u16* A = Xg + (size_t)(ti * 64 + qi * 32 + lc) * NP + kc * 1024 + half * 8;
  const u16* B = Xg + (size_t)(tj * 64 + qj * 32 + lc) * NP + kc * 1024 + half * 8;
  f32x16 acc;
#pragma unroll
  for (int i = 0; i < 16; ++i) acc[i] = 0.f;
#pragma unroll 4
  for (int s = 0; s < 64; ++s) {
    bf16x8 a = ldbf16x8(A + s * 16);
    bf16x8 b = ldbf16x8(B + s * 16);
    acc = __builtin_amdgcn_mfma_f32_32x32x16_bf16(a, b, acc, 0, 0, 0);
  }
  float* __restrict__ P = Cpart + (((size_t)g * 16 + tp) * 16 + kc) * 4096;
#pragma unroll
  for (int r = 0; r < 16; ++r) {
    const int row = qi * 32 + (r & 3) + 8 * (r >> 2) + 4 * half;
    const int col = qj * 32 + lc;
    P[row * 64 + col] = acc[r];
  }
}

// K1b (MFMA path): sum 16 K-chunk partials per tile -> C.
__global__ __launch_bounds__(256)
void k1b_red(const float* __restrict__ Cpart, float* __restrict__ Cmat) {
  const int sl = blockIdx.x;   // 16 slices of 256
  const int tp = blockIdx.y;   // 16
  const int g  = blockIdx.z;
  const int ele = sl * 256 + threadIdx.x;
  const float* __restrict__ P =
      Cpart + (((size_t)g * 16 + tp) * 16) * 4096 + ele;
  float v = 0.f;
#pragma unroll
  for (int kc = 0; kc < 16; ++kc) v += P[(size_t)kc * 4096];
  const int ti = tp >> 2, tj = tp & 3;
  const int r64 = ele >> 6, c64 = ele & 63;
  Cmat[(size_t)g * 65536 + (size_t)(ti * 64 + r64) * 256 + tj * 64 + c64] = v;
}

// ---------------------------------------------------------------------------
// Fallback tier 2: R6 fp32 split-K Gram (known-good, 66 us).
__global__ __launch_bounds__(256)
void k1_gram(const float* __restrict__ x, float* __restrict__ Cpart) {
  __shared__ float As[32 * 132];
  __shared__ float Bs[32 * 132];
  const int kc = blockIdx.x, ty = blockIdx.y, g = blockIdx.z;
  const int i0 = (ty == 2) ? 128 : 0;
  const int j0 = (ty == 0) ? 0 : 128;
  const float* __restrict__ Xg = x + (size_t)g * 256 * NP;
  const int tid = threadIdx.x, lane = tid & 63, w = tid >> 6;
  const int wy = (w >> 1) * 64, wx = (w & 1) * 64;
  const int ly = (lane >> 3) * 8, lx = (lane & 7) * 8;
  float acc[8][8];
#pragma unroll
  for (int e = 0; e < 8; ++e)
#pragma unroll
    for (int f = 0; f < 8; ++f) acc[e][f] = 0.f;
  const int k8 = (tid & 3) * 8, rowb = tid >> 2, k0 = kc * 256;
  for (int s = 0; s < 8; ++s) {
    const int ks = k0 + s * 32;
#pragma unroll
    for (int pass = 0; pass < 2; ++pass) {
      const int row = rowb + pass * 64;
      const size_t ea = (size_t)(i0 + row) * NP + ks + k8;
      float4 a = *(const float4*)(Xg + ea);
      float4 b = *(const float4*)(Xg + ea + 4);
      As[(k8+0)*132+row]=a.x; As[(k8+1)*132+row]=a.y;
      As[(k8+2)*132+row]=a.z; As[(k8+3)*132+row]=a.w;
      As[(k8+4)*132+row]=b.x; As[(k8+5)*132+row]=b.y;
      As[(k8+6)*132+row]=b.z; As[(k8+7)*132+row]=b.w;
      const size_t eb = (size_t)(j0 + row) * NP + ks + k8;
      a = *(const float4*)(Xg + eb);
      b = *(const float4*)(Xg + eb + 4);
      Bs[(k8+0)*132+row]=a.x; Bs[(k8+1)*132+row]=a.y;
      Bs[(k8+2)*132+row]=a.z; Bs[(k8+3)*132+row]=a.w;
      Bs[(k8+4)*132+row]=b.x; Bs[(k8+5)*132+row]=b.y;
      Bs[(k8+6)*132+row]=b.z; Bs[(k8+7)*132+row]=b.w;
    }
    __syncthreads();
#pragma unroll 4
    for (int kk = 0; kk < 32; ++kk) {
      const float* ar = &As[kk * 132 + wy + ly];
      const float* br = &Bs[kk * 132 + wx + lx];
      float4 a0 = *(const float4*)(ar), a1 = *(const float4*)(ar + 4);
      float4 b0 = *(const float4*)(br), b1 = *(const float4*)(br + 4);
      const float av[8] = {a0.x,a0.y,a0.z,a0.w,a1.x,a1.y,a1.z,a1.w};
      const float bv[8] = {b0.x,b0.y,b0.z,b0.w,b1.x,b1.y,b1.z,b1.w};
#pragma unroll
      for (int e = 0; e < 8; ++e)
#pragma unroll
        for (int f = 0; f < 8; ++f) acc[e][f] += av[e] * bv[f];
    }
    __syncthreads();
  }
  float* __restrict__ P = Cpart + (((size_t)g * 3 + ty) * 64 + kc) * 16384;
#pragma unroll
  for (int e = 0; e < 8; ++e) {
    float* pr = P + (size_t)(wy + ly + e) * 128 + wx + lx;
    float4 s0 = {acc[e][0], acc[e][1], acc[e][2], acc[e][3]};
    float4 s1 = {acc[e][4], acc[e][5], acc[e][6], acc[e][7]};
    *(float4*)(pr)     = s0;
    *(float4*)(pr + 4) = s1;
  }
}

__global__ __launch_bounds__(256)
void k1b_reduce(const float* __restrict__ Cpart, float* __restrict__ Cmat) {
  const int sl = blockIdx.x, ty = blockIdx.y, g = blockIdx.z;
  const int ele = sl * 256 + threadIdx.x;
  const float* __restrict__ P =
      Cpart + (((size_t)g * 3 + ty) * 64) * 16384 + ele;
  float v = 0.f;
#pragma unroll 8
  for (int kc = 0; kc < 64; ++kc) v += P[(size_t)kc * 16384];
  const int i0 = (ty == 2) ? 128 : 0;
  const int j0 = (ty == 0) ? 0 : 128;
  const int i = ele >> 7, j = ele & 127;
  float* Cg = Cmat + (size_t)g * 65536;
  Cg[(size_t)(i0 + i) * 256 + (j0 + j)] = v;
  if (ty == 1) Cg[(size_t)(j0 + j) * 256 + (i0 + i)] = v;
}

// Fallback tier 3 (tiny ws): atomic Gram.
__global__ __launch_bounds__(256)
void k1_gram_atomic(const float* __restrict__ x, float* __restrict__ Cmat) {
  __shared__ float As[32 * 132];
  __shared__ float Bs[32 * 132];
  const int kc = blockIdx.x, ty = blockIdx.y, g = blockIdx.z;
  const int i0 = (ty == 2) ? 128 : 0;
  const int j0 = (ty == 0) ? 0 : 128;
  const float* __restrict__ Xg = x + (size_t)g * 256 * NP;
  const int tid = threadIdx.x, lane = tid & 63, w = tid >> 6;
  const int wy = (w >> 1) * 64, wx = (w & 1) * 64;
  const int ly = (lane >> 3) * 8, lx = (lane & 7) * 8;
  float acc[8][8];
#pragma unroll
  for (int e = 0; e < 8; ++e)
#pragma unroll
    for (int f = 0; f < 8; ++f) acc[e][f] = 0.f;
  const int k8 = (tid & 3) * 8, rowb = tid >> 2, k0 = kc * 256;
  for (int s = 0; s < 8; ++s) {
    const int ks = k0 + s * 32;
#pragma unroll
    for (int pass = 0; pass < 2; ++pass) {
      const int row = rowb + pass * 64;
      const size_t ea = (size_t)(i0 + row) * NP + ks + k8;
      float4 a = *(const float4*)(Xg + ea);
      float4 b = *(const float4*)(Xg + ea + 4);
      As[(k8+0)*132+row]=a.x; As[(k8+1)*132+row]=a.y;
      As[(k8+2)*132+row]=a.z; As[(k8+3)*132+row]=a.w;
      As[(k8+4)*132+row]=b.x; As[(k8+5)*132+row]=b.y;
      As[(k8+6)*132+row]=b.z; As[(k8+7)*132+row]=b.w;
      const size_t eb = (size_t)(j0 + row) * NP + ks + k8;
      a = *(const float4*)(Xg + eb);
      b = *(const float4*)(Xg + eb + 4);
      Bs[(k8+0)*132+row]=a.x; Bs[(k8+1)*132+row]=a.y;
      Bs[(k8+2)*132+row]=a.z; Bs[(k8+3)*132+row]=a.w;
      Bs[(k8+4)*132+row]=b.x; Bs[(k8+5)*132+row]=b.y;
      Bs[(k8+6)*132+row]=b.z; Bs[(k8+7)*132+row]=b.w;
    }
    __syncthreads();
#pragma unroll 4
    for (int kk = 0; kk < 32; ++kk) {
      const float* ar = &As[kk * 132 + wy + ly];
      const float* br = &Bs[kk * 132 + wx + lx];
      float4 a0 = *(const float4*)(ar), a1 = *(const float4*)(ar + 4);
      float4 b0 = *(const float4*)(br), b1 = *(const float4*)(br + 4);
      const float av[8] = {a0.x,a0.y,a0.z,a0.w,a1.x,a1.y,a1.z,a1.w};
      const float bv[8] = {b0.x,b0.y,b0.z,b0.w,b1.x,b1.y,b1.z,b1.w};
#pragma unroll
      for (int e = 0; e < 8; ++e)
#pragma unroll
        for (int f = 0; f < 8; ++f) acc[e][f] += av[e] * bv[f];
    }
    __syncthreads();
  }
  float* Cg = Cmat + (size_t)g * 65536;
#pragma unroll
  for (int e = 0; e < 8; ++e)
#pragma unroll
    for (int f = 0; f < 8; ++f) {
      atomicAdd(&Cg[(i0+wy+ly+e)*256 + (j0+wx+lx+f)], acc[e][f]);
      if (ty == 1)
        atomicAdd(&Cg[(j0+wx+lx+f)*256 + (i0+wy+ly+e)], acc[e][f]);
    }
}

// ---------------------------------------------------------------------------
// K2: T[bh][i][a] = sum_b Wq[hh*64+i][b] * C[g][b][a].
__global__ __launch_bounds__(256) void k2_T(const float* __restrict__ Wq,
                                            const float* __restrict__ Cmat,
                                            float* __restrict__ T) {
  const int bh = blockIdx.x;
  const int ic = blockIdx.y;
  const int g = bh >> 3, hh = bh & 7;
  const int tid = threadIdx.x;
  const float* __restrict__ Cg = Cmat + (size_t)g * 65536;
  const int r0 = hh * 64 + ic * 4;
  float acc[4] = {0.f, 0.f, 0.f, 0.f};
#pragma unroll 8
  for (int b = 0; b < 256; ++b) {
    const float cv = Cg[(size_t)b * 256 + tid];
#pragma unroll
    for (int ii = 0; ii < 4; ++ii)
      acc[ii] += Wq[(size_t)(r0 + ii) * 256 + b] * cv;
  }
#pragma unroll
  for (int ii = 0; ii < 4; ++ii)
    T[((size_t)bh * 64 + ic * 4 + ii) * 256 + tid] = acc[ii];
}

// ---------------------------------------------------------------------------
// K3: sim[bh][i][j] = 0.125 * sum_a T[bh][i][a] * Wk[hh*64+j][a].
__global__ __launch_bounds__(256) void k3_sim(const float* __restrict__ Wkv,
                                              const float* __restrict__ T,
                                              float* __restrict__ simattn) {
  __shared__ float Ts[64 * 256];
  const int bh = blockIdx.x;
  const int jc = blockIdx.y;
  const int hh = bh & 7;
  const int tid = threadIdx.x;
  {
    const int f4i = tid & 63;
    const int rwb = tid >> 6;
    for (int pass = 0; pass < 16; ++pass) {
      const int row = rwb + pass * 4;
      float4 v = *(const float4*)(T + ((size_t)bh * 64 + row) * 256 + f4i * 4);
      const int a0 = f4i * 4;
      const float vv[4] = {v.x, v.y, v.z, v.w};
#pragma unroll
      for (int e = 0; e < 4; ++e) {
        const int a = a0 + e;
        Ts[row * 256 + (a & ~31) + ((a + row) & 31)] = vv[e];
      }
    }
  }
  __syncthreads();
  const int i  = tid & 63;
  const int jq = tid >> 6;
  const int jb = jc * 16 + jq * 4;
  float acc[4] = {0.f, 0.f, 0.f, 0.f};
#pragma unroll 4
  for (int a = 0; a < 256; ++a) {
    const float tv = Ts[i * 256 + (a & ~31) + ((a + i) & 31)];
#pragma unroll
    for (int jj = 0; jj < 4; ++jj)
      acc[jj] += Wkv[(size_t)(hh * 64 + jb + jj) * 256 + a] * tv;
  }
#pragma unroll
  for (int jj = 0; jj < 4; ++jj)
    simattn[((size_t)bh * 64 + i) * 64 + jb + jj] = acc[jj] * 0.125f;
}

// K3b: row softmax.
__global__ __launch_bounds__(64) void k3b_softmax(float* __restrict__ simattn) {
  const int bh = blockIdx.x;
  const int i  = threadIdx.x;
  float* row = simattn + ((size_t)bh * 64 + i) * 64;
  float v[64];
  float m = -1e30f;
#pragma unroll
  for (int j = 0; j < 64; ++j) { v[j] = row[j]; m = fmaxf(m, v[j]); }
  float s = 0.f;
#pragma unroll
  for (int j = 0; j < 64; ++j) { v[j] = __expf(v[j] - m); s += v[j]; }
  const float inv = 1.0f / s;
#pragma unroll
  for (int j = 0; j < 64; ++j) row[j] = v[j] * inv;
}

// ---------------------------------------------------------------------------
// K4: WeT[g][hh*64+j][co] = sum_i Wout[co][hh*64+i] * attn[bh][i][j].
__global__ __launch_bounds__(256) void k4_we(const float* __restrict__ Wout,
                                             const float* __restrict__ attn,
                                             float* __restrict__ WeT) {
  __shared__ float WL[256 * 64];
  const int jc = blockIdx.x;
  const int hh = blockIdx.y;
  const int g  = blockIdx.z;
  const int bh = g * 8 + hh;
  const int tid = threadIdx.x;
  {
    const int f4i = tid & 15;
    const int cb  = tid >> 4;
    for (int pass = 0; pass < 16; ++pass) {
      const int co = cb + pass * 16;
      float4 v = *(const float4*)(Wout + (size_t)co * 512 + hh * 64 + f4i * 4);
      const int a0 = f4i * 4;
      const float vv[4] = {v.x, v.y, v.z, v.w};
#pragma unroll
      for (int e = 0; e < 4; ++e)
        WL[co * 64 + ((a0 + e + co) & 63)] = vv[e];
    }
  }
  __syncthreads();
  const int jb = jc * 8;
  float acc[8] = {0.f, 0.f, 0.f, 0.f, 0.f, 0.f, 0.f, 0.f};
#pragma unroll 4
  for (int i = 0; i < 64; ++i) {
    const float wv = WL[tid * 64 + ((i + tid) & 63)];
#pragma unroll
    for (int je = 0; je < 8; ++je)
      acc[je] += attn[((size_t)bh * 64 + i) * 64 + jb + je] * wv;
  }
#pragma unroll
  for (int je = 0; je < 8; ++je)
    WeT[(size_t)g * 131072 + (size_t)(hh * 64 + jb + je) * 256 + tid] =
        acc[je];
}

// ---------------------------------------------------------------------------
// K5: Mt[g][b][co] (fp32, fallback k6) and M_A[g][co][b] (bf16, MFMA k6).
__global__ __launch_bounds__(256) void k5_M(const float* __restrict__ Wkv,
                                            const float* __restrict__ WeT,
                                            float* __restrict__ Mt,
                                            u16* __restrict__ MA) {
  const int bc = blockIdx.x;
  const int g  = blockIdx.y;
  const int tid = threadIdx.x;  // co lane
  const int b0 = bc * 4;
  const float* __restrict__ Weg = WeT + (size_t)g * 131072;
  float acc[4] = {0.f, 0.f, 0.f, 0.f};
#pragma unroll 4
  for (int o = 0; o < 512; ++o) {
    const float wv = Weg[(size_t)o * 256 + tid];
    const float* __restrict__ vr = Wkv + (size_t)(512 + o) * 256 + b0;
    acc[0] += vr[0] * wv;
    acc[1] += vr[1] * wv;
    acc[2] += vr[2] * wv;
    acc[3] += vr[3] * wv;
  }
#pragma unroll
  for (int be = 0; be < 4; ++be) {
    Mt[(size_t)g * 65536 + (size_t)(b0 + be) * 256 + tid] = acc[be];
    MA[(size_t)g * 65536 + (size_t)tid * 256 + b0 + be] = f2bf(acc[be]);
  }
}

// ---------------------------------------------------------------------------
// K6 (MFMA): D[p][co] = sum_f XbT[p][f]*M_A[co][f]; out[co][p] = D + bout[co].
// A = XbT (m=p, k=f contiguous); B = M_A (n=co, k=f contiguous).  C/D layout
// gives each lane a fixed co and p-contiguous rows -> float4 output stores.
__global__ __launch_bounds__(256)
void k6_mfma(const u16* __restrict__ XbT, const u16* __restrict__ MA,
             const float* __restrict__ bout, float* __restrict__ out) {
  const int pb = blockIdx.x;   // 128 p-blocks of 128
  const int cb = blockIdx.y;   // 2 co-blocks of 128
  const int g  = blockIdx.z;
  const int tid = threadIdx.x;
  const int w = tid >> 6, half = (tid >> 5) & 1, lc = tid & 31;
  const int p0  = pb * 128 + w * 32;
  const int co0 = cb * 128;
  const u16* __restrict__ Ap =
      XbT + ((size_t)g * NP + p0 + lc) * 256 + half * 8;
  const u16* __restrict__ Mg = MA + (size_t)g * 65536;
  f32x16 acc[4];
#pragma unroll
  for (int t = 0; t < 4; ++t)
#pragma unroll
    for (int i = 0; i < 16; ++i) acc[t][i] = 0.f;
#pragma unroll 2
  for (int s = 0; s < 16; ++s) {
    bf16x8 a = ldbf16x8(Ap + s * 16);
#pragma unroll
    for (int t = 0; t < 4; ++t) {
      bf16x8 b =
          ldbf16x8(Mg + (size_t)(co0 + t * 32 + lc) * 256 + half * 8 + s * 16);
      acc[t] = __builtin_amdgcn_mfma_f32_32x32x16_bf16(a, b, acc[t], 0, 0, 0);
    }
  }
#pragma unroll
  for (int t = 0; t < 4; ++t) {
    const int co = co0 + t * 32 + lc;
    const float bo = bout[co];
    float* __restrict__ ocol =
        out + ((size_t)(g * 256 + co)) * NP + p0 + 4 * half;
#pragma unroll
    for (int rg = 0; rg < 4; ++rg) {
      float4 v = {acc[t][rg * 4 + 0] + bo, acc[t][rg * 4 + 1] + bo,
                  acc[t][rg * 4 + 2] + bo, acc[t][rg * 4 + 3] + bo};
      *(float4*)(ocol + rg * 8) = v;
    }
  }
}

// Fallback fp32 K6 (R6 version).
__global__ __launch_bounds__(256)
void k6_apply(const float* __restrict__ x, const float* __restrict__ Mt,
              const float* __restrict__ bout, float* __restrict__ out) {
  __shared__ float As[32 * 132];
  __shared__ float Bs[32 * 132];
  const int pc = blockIdx.x;
  const int oy = blockIdx.y;
  const int g  = blockIdx.z;
  const int p0 = pc * 128;
  const int o0 = oy * 128;
  const float* __restrict__ Xg = x + (size_t)g * 256 * NP;
  const float* __restrict__ Mg = Mt + (size_t)g * 65536;
  const int tid  = threadIdx.x;
  const int lane = tid & 63;
  const int w    = tid >> 6;
  const int wy = (w >> 1) * 64;
  const int wx = (w & 1) * 64;
  const int ly = (lane >> 3) * 8;
  const int lx = (lane & 7) * 8;
  float acc[8][8];
#pragma unroll
  for (int e = 0; e < 8; ++e)
#pragma unroll
    for (int f = 0; f < 8; ++f) acc[e][f] = 0.f;
  const int c4 = (tid & 31) * 4;
  const int kb = tid >> 5;
  for (int s = 0; s < 8; ++s) {
#pragma unroll
    for (int r = 0; r < 4; ++r) {
      const int kk = kb + r * 8;
      const int f  = s * 32 + kk;
      *(float4*)&As[kk * 132 + c4] =
          *(const float4*)(Mg + (size_t)f * 256 + o0 + c4);
      *(float4*)&Bs[kk * 132 + c4] =
          *(const float4*)(Xg + (size_t)f * NP + p0 + c4);
    }
    __syncthreads();
#pragma unroll 4
    for (int kk = 0; kk < 32; ++kk) {
      const float* __restrict__ ar = &As[kk * 132 + wy + ly];
      const float* __restrict__ br = &Bs[kk * 132 + wx + lx];
      float4 a0 = *(const float4*)(ar);
      float4 a1 = *(const float4*)(ar + 4);
      float4 b0 = *(const float4*)(br);
      float4 b1 = *(const float4*)(br + 4);
      const float av[8] = {a0.x, a0.y, a0.z, a0.w, a1.x, a1.y, a1.z, a1.w};
      const float bv[8] = {b0.x, b0.y, b0.z, b0.w, b1.x, b1.y, b1.z, b1.w};
#pragma unroll
      for (int e = 0; e < 8; ++e)
#pragma unroll
        for (int f = 0; f < 8; ++f) acc[e][f] += av[e] * bv[f];
    }
    __syncthreads();
  }
#pragma unroll
  for (int e = 0; e < 8; ++e) {
    const int co = o0 + wy + ly + e;
    const float bo = bout[co];
    float* __restrict__ orow =
        out + ((size_t)(g * 256 + co)) * NP + p0 + wx + lx;
    float4 s0 = {acc[e][0] + bo, acc[e][1] + bo, acc[e][2] + bo,
                 acc[e][3] + bo};
    float4 s1 = {acc[e][4] + bo, acc[e][5] + bo, acc[e][6] + bo,
                 acc[e][7] + bo};
    *(float4*)(orow)     = s0;
    *(float4*)(orow + 4) = s1;
  }
}

// ---------------------------------------------------------------------------
extern "C" void kernel_launch(void* const* d_in, const int* in_sizes, int n_in,
                              void* d_out, int out_size, void* d_ws,
                              size_t ws_size, hipStream_t stream) {
  const float* x    = (const float*)d_in[0];
  const float* Wq   = (const float*)d_in[1];
  const float* Wkv  = (const float*)d_in[2];
  const float* Wout = (const float*)d_in[3];
  const float* bout = (const float*)d_in[4];
  float* out = (float*)d_out;
  float* ws  = (float*)d_ws;

  float* C    = ws + OFF_C;
  float* T    = ws + OFF_T;
  float* att  = ws + OFF_AT;
  float* WeT  = ws + OFF_WE;
  float* Mt   = ws + OFF_MT;
  u16*   MA   = (u16*)(ws + OFF_MA);
  u16*   Xb   = (u16*)(ws + OFF_XB);
  u16*   XbT  = (u16*)(ws + OFF_XBT);
  float* Cp1  = ws + OFF_CP1;
  float* Cp2  = ws + OFF_CP2;

  const bool mfma_path = (ws_size >= NEED1);

  if (mfma_path) {
    k0_cvt<<<dim3(256, 2), 256, 0, stream>>>(x, Xb, XbT);
    k1_mfma<<<dim3(16, 16, 2), 256, 0, stream>>>(Xb, Cp1);
    k1b_red<<<dim3(16, 16, 2), 256, 0, stream>>>(Cp1, C);
  } else if (ws_size >= NEED2) {
    k1_gram<<<dim3(64, 3, 2), 256, 0, stream>>>(x, Cp2);
    k1b_reduce<<<dim3(64, 3, 2), 256, 0, stream>>>(Cp2, C);
  } else {
    hipMemsetAsync(C, 0, 131072 * sizeof(float), stream);
    k1_gram_atomic<<<dim3(64, 3, 2), 256, 0, stream>>>(x, C);
  }
  k2_T<<<dim3(16, 16), 256, 0, stream>>>(Wq, C, T);
  k3_sim<<<dim3(16, 4), 256, 0, stream>>>(Wkv, T, att);
  k3b_softmax<<<dim3(16), 64, 0, stream>>>(att);
  k4_we<<<dim3(8, 8, 2), 256, 0, stream>>>(Wout, att, WeT);
  k5_M<<<dim3(64, 2), 256, 0, stream>>>(Wkv, WeT, Mt, MA);
  if (mfma_path) {
    k6_mfma<<<dim3(128, 2, 2), 256, 0, stream>>>(XbT, MA, bout, out);
  } else {
    k6_apply<<<dim3(128, 2, 2), 256, 0, stream>>>(x, Mt, bout, out);
  }
}

// Round 8
// 199.118 us; speedup vs baseline: 3.2161x; 1.1419x over previous
//
#include <hip/hip_runtime.h>
#include <cstdint>
#include <cstddef>

using u16 = unsigned short;
using u32 = unsigned int;

typedef __attribute__((ext_vector_type(8))) short bf16x8;   // 8 bf16 = 4 VGPRs
typedef __attribute__((ext_vector_type(16))) float f32x16;  // MFMA 32x32 acc

__device__ __forceinline__ u16 f2bf(float f) {  // round-to-nearest-even
  union { float f; u32 i; } x; x.f = f;
  u32 r = (x.i + 0x7FFFu + ((x.i >> 16) & 1u)) >> 16;
  return (u16)r;
}
__device__ __forceinline__ bf16x8 ldbf16x8(const u16* p) {
  union { uint4 u; bf16x8 v; } t;
  t.u = *(const uint4*)p;
  return t.v;
}

// Geometry: x (16,32,128,128) fp32 -> G=2 groups, F=256 features/group,
// N=16384 positions, 8 heads/group, dim_head=64.  Collapse:
// C[g]=F·F^T Gram; sim=Wq_h·C·Wk_h^T; attn=softmax; M=(Wout·bd(attn))·Wv;
// out = M·f + bout.
constexpr int NP = 16384;

// ws layout (fp32 element offsets)
constexpr size_t OFF_C   = 0;        // C[2][256][256]        131072
constexpr size_t OFF_T   = 131072;   // T[16][64][256]        262144
constexpr size_t OFF_AT  = 393216;   // sim/attn[16][64][64]   65536
constexpr size_t OFF_WE  = 458752;   // WeT[2][512][256]      262144
constexpr size_t OFF_MT  = 720896;   // Mt fp32 [2][256][256] 131072
constexpr size_t OFF_MA  = 851968;   // M_A bf16 [2][256co][256f] (65536 fl)
constexpr size_t OFF_XB  = 917504;   // Xb  bf16 [2][256f][16384p] (4194304 fl)
constexpr size_t OFF_XBT = 5111808;  // XbT bf16 [2][16384p][256f] (4194304 fl)
constexpr size_t OFF_CP1 = 9306112;  // Cpart1 [2][16tp][16kc][4096] (2097152 fl)
                                     // reused after k1b as k5 partials
                                     // Mp[2][16oc][256b][256co] (2097152 fl)
constexpr size_t NEED1   = (OFF_CP1 + 2097152) * 4;  // 45,613,056 B
constexpr size_t OFF_CP2 = 851968;   // fp32-fallback partials (6291456 fl)
constexpr size_t NEED2   = (OFF_CP2 + 6291456) * 4;  // 28,573,696 B

// ---------------------------------------------------------------------------
// K0: x fp32 -> Xb bf16 (same layout) + XbT bf16 (transposed, for k6's A).
// 256f x 64p slab per block; LDS transpose with pad-65 rows.
__global__ __launch_bounds__(256)
void k0_cvt(const float* __restrict__ x, u16* __restrict__ Xb,
            u16* __restrict__ XbT) {
  __shared__ float Fs[256 * 65];
  const int pc = blockIdx.x;   // 256 chunks of 64 positions
  const int g  = blockIdx.y;
  const int p0 = pc * 64;
  const float* __restrict__ Xg = x + (size_t)g * 256 * NP;
  u16* __restrict__ Xbg  = Xb  + (size_t)g * 256 * NP;
  u16* __restrict__ XbTg = XbT + (size_t)g * NP * 256;
  const int tid = threadIdx.x;
  const int f8i = tid & 7, rb = tid >> 3;
  for (int pass = 0; pass < 8; ++pass) {
    const int row = rb + pass * 32;
    const size_t e0 = (size_t)row * NP + p0 + f8i * 8;
    float4 a = *(const float4*)(Xg + e0);
    float4 b = *(const float4*)(Xg + e0 + 4);
    const float v[8] = {a.x, a.y, a.z, a.w, b.x, b.y, b.z, b.w};
    uint4 s;
    s.x = (u32)f2bf(v[0]) | ((u32)f2bf(v[1]) << 16);
    s.y = (u32)f2bf(v[2]) | ((u32)f2bf(v[3]) << 16);
    s.z = (u32)f2bf(v[4]) | ((u32)f2bf(v[5]) << 16);
    s.w = (u32)f2bf(v[6]) | ((u32)f2bf(v[7]) << 16);
    *(uint4*)(Xbg + e0) = s;
    float* d = &Fs[row * 65 + f8i * 8];
#pragma unroll
    for (int e = 0; e < 8; ++e) d[e] = v[e];
  }
  __syncthreads();
  const int p = tid & 63, grp = tid >> 6;
  u16* dst = XbTg + (size_t)(p0 + p) * 256 + grp * 64;
  for (int c = 0; c < 4; ++c) {
    u32 w[8];
#pragma unroll
    for (int q = 0; q < 8; ++q) {
      const int f = grp * 64 + c * 16 + q * 2;
      u32 lo = f2bf(Fs[f * 65 + p]);
      u32 hi = f2bf(Fs[(f + 1) * 65 + p]);
      w[q] = lo | (hi << 16);
    }
    uint4 s0 = {w[0], w[1], w[2], w[3]};
    uint4 s1 = {w[4], w[5], w[6], w[7]};
    *(uint4*)(dst + c * 16)     = s0;
    *(uint4*)(dst + c * 16 + 8) = s1;
  }
}

// ---------------------------------------------------------------------------
// K1 (MFMA): Cpart[g][tp][kc] = 64x64 tile of Xb·Xb^T over a 1024-pos K-chunk.
// 4 waves = 2x2 quadrants of 32x32; v_mfma_f32_32x32x16_bf16, fp32 acc.
// Layouts (learn_hip-verified): A[m=l&31][k=(l>>5)*8+j]; B mirrored;
// C/D row=(r&3)+8*(r>>2)+4*(l>>5), col=l&31.
__global__ __launch_bounds__(256)
void k1_mfma(const u16* __restrict__ Xb, float* __restrict__ Cpart) {
  const int kc = blockIdx.x;   // 16 chunks of 1024 positions
  const int tp = blockIdx.y;   // 16 tile positions (4x4 of 64x64)
  const int g  = blockIdx.z;
  const int ti = tp >> 2, tj = tp & 3;
  const int tid = threadIdx.x;
  const int w = tid >> 6, half = (tid >> 5) & 1, lc = tid & 31;
  const int qi = w >> 1, qj = w & 1;
  const u16* __restrict__ Xg = Xb + (size_t)g * 256 * NP;
  const u16* A = Xg + (size_t)(ti * 64 + qi * 32 + lc) * NP + kc * 1024 + half * 8;
  const u16* B = Xg + (size_t)(tj * 64 + qj * 32 + lc) * NP + kc * 1024 + half * 8;
  f32x16 acc;
#pragma unroll
  for (int i = 0; i < 16; ++i) acc[i] = 0.f;
#pragma unroll 4
  for (int s = 0; s < 64; ++s) {
    bf16x8 a = ldbf16x8(A + s * 16);
    bf16x8 b = ldbf16x8(B + s * 16);
    acc = __builtin_amdgcn_mfma_f32_32x32x16_bf16(a, b, acc, 0, 0, 0);
  }
  float* __restrict__ P = Cpart + (((size_t)g * 16 + tp) * 16 + kc) * 4096;
#pragma unroll
  for (int r = 0; r < 16; ++r) {
    const int row = qi * 32 + (r & 3) + 8 * (r >> 2) + 4 * half;
    const int col = qj * 32 + lc;
    P[row * 64 + col] = acc[r];
  }
}

// K1b (MFMA path): sum 16 K-chunk partials per tile -> C.
__global__ __launch_bounds__(256)
void k1b_red(const float* __restrict__ Cpart, float* __restrict__ Cmat) {
  const int sl = blockIdx.x;   // 16 slices of 256
  const int tp = blockIdx.y;   // 16
  const int g  = blockIdx.z;
  const int ele = sl * 256 + threadIdx.x;
  const float* __restrict__ P =
      Cpart + (((size_t)g * 16 + tp) * 16) * 4096 + ele;
  float v = 0.f;
#pragma unroll
  for (int kc = 0; kc < 16; ++kc) v += P[(size_t)kc * 4096];
  const int ti = tp >> 2, tj = tp & 3;
  const int r64 = ele >> 6, c64 = ele & 63;
  Cmat[(size_t)g * 65536 + (size_t)(ti * 64 + r64) * 256 + tj * 64 + c64] = v;
}

// ---------------------------------------------------------------------------
// Fallback tier 2: R6 fp32 split-K Gram (known-good, 66 us).
__global__ __launch_bounds__(256)
void k1_gram(const float* __restrict__ x, float* __restrict__ Cpart) {
  __shared__ float As[32 * 132];
  __shared__ float Bs[32 * 132];
  const int kc = blockIdx.x, ty = blockIdx.y, g = blockIdx.z;
  const int i0 = (ty == 2) ? 128 : 0;
  const int j0 = (ty == 0) ? 0 : 128;
  const float* __restrict__ Xg = x + (size_t)g * 256 * NP;
  const int tid = threadIdx.x, lane = tid & 63, w = tid >> 6;
  const int wy = (w >> 1) * 64, wx = (w & 1) * 64;
  const int ly = (lane >> 3) * 8, lx = (lane & 7) * 8;
  float acc[8][8];
#pragma unroll
  for (int e = 0; e < 8; ++e)
#pragma unroll
    for (int f = 0; f < 8; ++f) acc[e][f] = 0.f;
  const int k8 = (tid & 3) * 8, rowb = tid >> 2, k0 = kc * 256;
  for (int s = 0; s < 8; ++s) {
    const int ks = k0 + s * 32;
#pragma unroll
    for (int pass = 0; pass < 2; ++pass) {
      const int row = rowb + pass * 64;
      const size_t ea = (size_t)(i0 + row) * NP + ks + k8;
      float4 a = *(const float4*)(Xg + ea);
      float4 b = *(const float4*)(Xg + ea + 4);
      As[(k8+0)*132+row]=a.x; As[(k8+1)*132+row]=a.y;
      As[(k8+2)*132+row]=a.z; As[(k8+3)*132+row]=a.w;
      As[(k8+4)*132+row]=b.x; As[(k8+5)*132+row]=b.y;
      As[(k8+6)*132+row]=b.z; As[(k8+7)*132+row]=b.w;
      const size_t eb = (size_t)(j0 + row) * NP + ks + k8;
      a = *(const float4*)(Xg + eb);
      b = *(const float4*)(Xg + eb + 4);
      Bs[(k8+0)*132+row]=a.x; Bs[(k8+1)*132+row]=a.y;
      Bs[(k8+2)*132+row]=a.z; Bs[(k8+3)*132+row]=a.w;
      Bs[(k8+4)*132+row]=b.x; Bs[(k8+5)*132+row]=b.y;
      Bs[(k8+6)*132+row]=b.z; Bs[(k8+7)*132+row]=b.w;
    }
    __syncthreads();
#pragma unroll 4
    for (int kk = 0; kk < 32; ++kk) {
      const float* ar = &As[kk * 132 + wy + ly];
      const float* br = &Bs[kk * 132 + wx + lx];
      float4 a0 = *(const float4*)(ar), a1 = *(const float4*)(ar + 4);
      float4 b0 = *(const float4*)(br), b1 = *(const float4*)(br + 4);
      const float av[8] = {a0.x,a0.y,a0.z,a0.w,a1.x,a1.y,a1.z,a1.w};
      const float bv[8] = {b0.x,b0.y,b0.z,b0.w,b1.x,b1.y,b1.z,b1.w};
#pragma unroll
      for (int e = 0; e < 8; ++e)
#pragma unroll
        for (int f = 0; f < 8; ++f) acc[e][f] += av[e] * bv[f];
    }
    __syncthreads();
  }
  float* __restrict__ P = Cpart + (((size_t)g * 3 + ty) * 64 + kc) * 16384;
#pragma unroll
  for (int e = 0; e < 8; ++e) {
    float* pr = P + (size_t)(wy + ly + e) * 128 + wx + lx;
    float4 s0 = {acc[e][0], acc[e][1], acc[e][2], acc[e][3]};
    float4 s1 = {acc[e][4], acc[e][5], acc[e][6], acc[e][7]};
    *(float4*)(pr)     = s0;
    *(float4*)(pr + 4) = s1;
  }
}

__global__ __launch_bounds__(256)
void k1b_reduce(const float* __restrict__ Cpart, float* __restrict__ Cmat) {
  const int sl = blockIdx.x, ty = blockIdx.y, g = blockIdx.z;
  const int ele = sl * 256 + threadIdx.x;
  const float* __restrict__ P =
      Cpart + (((size_t)g * 3 + ty) * 64) * 16384 + ele;
  float v = 0.f;
#pragma unroll 8
  for (int kc = 0; kc < 64; ++kc) v += P[(size_t)kc * 16384];
  const int i0 = (ty == 2) ? 128 : 0;
  const int j0 = (ty == 0) ? 0 : 128;
  const int i = ele >> 7, j = ele & 127;
  float* Cg = Cmat + (size_t)g * 65536;
  Cg[(size_t)(i0 + i) * 256 + (j0 + j)] = v;
  if (ty == 1) Cg[(size_t)(j0 + j) * 256 + (i0 + i)] = v;
}

// Fallback tier 3 (tiny ws): atomic Gram.
__global__ __launch_bounds__(256)
void k1_gram_atomic(const float* __restrict__ x, float* __restrict__ Cmat) {
  __shared__ float As[32 * 132];
  __shared__ float Bs[32 * 132];
  const int kc = blockIdx.x, ty = blockIdx.y, g = blockIdx.z;
  const int i0 = (ty == 2) ? 128 : 0;
  const int j0 = (ty == 0) ? 0 : 128;
  const float* __restrict__ Xg = x + (size_t)g * 256 * NP;
  const int tid = threadIdx.x, lane = tid & 63, w = tid >> 6;
  const int wy = (w >> 1) * 64, wx = (w & 1) * 64;
  const int ly = (lane >> 3) * 8, lx = (lane & 7) * 8;
  float acc[8][8];
#pragma unroll
  for (int e = 0; e < 8; ++e)
#pragma unroll
    for (int f = 0; f < 8; ++f) acc[e][f] = 0.f;
  const int k8 = (tid & 3) * 8, rowb = tid >> 2, k0 = kc * 256;
  for (int s = 0; s < 8; ++s) {
    const int ks = k0 + s * 32;
#pragma unroll
    for (int pass = 0; pass < 2; ++pass) {
      const int row = rowb + pass * 64;
      const size_t ea = (size_t)(i0 + row) * NP + ks + k8;
      float4 a = *(const float4*)(Xg + ea);
      float4 b = *(const float4*)(Xg + ea + 4);
      As[(k8+0)*132+row]=a.x; As[(k8+1)*132+row]=a.y;
      As[(k8+2)*132+row]=a.z; As[(k8+3)*132+row]=a.w;
      As[(k8+4)*132+row]=b.x; As[(k8+5)*132+row]=b.y;
      As[(k8+6)*132+row]=b.z; As[(k8+7)*132+row]=b.w;
      const size_t eb = (size_t)(j0 + row) * NP + ks + k8;
      a = *(const float4*)(Xg + eb);
      b = *(const float4*)(Xg + eb + 4);
      Bs[(k8+0)*132+row]=a.x; Bs[(k8+1)*132+row]=a.y;
      Bs[(k8+2)*132+row]=a.z; Bs[(k8+3)*132+row]=a.w;
      Bs[(k8+4)*132+row]=b.x; Bs[(k8+5)*132+row]=b.y;
      Bs[(k8+6)*132+row]=b.z; Bs[(k8+7)*132+row]=b.w;
    }
    __syncthreads();
#pragma unroll 4
    for (int kk = 0; kk < 32; ++kk) {
      const float* ar = &As[kk * 132 + wy + ly];
      const float* br = &Bs[kk * 132 + wx + lx];
      float4 a0 = *(const float4*)(ar), a1 = *(const float4*)(ar + 4);
      float4 b0 = *(const float4*)(br), b1 = *(const float4*)(br + 4);
      const float av[8] = {a0.x,a0.y,a0.z,a0.w,a1.x,a1.y,a1.z,a1.w};
      const float bv[8] = {b0.x,b0.y,b0.z,b0.w,b1.x,b1.y,b1.z,b1.w};
#pragma unroll
      for (int e = 0; e < 8; ++e)
#pragma unroll
        for (int f = 0; f < 8; ++f) acc[e][f] += av[e] * bv[f];
    }
    __syncthreads();
  }
  float* Cg = Cmat + (size_t)g * 65536;
#pragma unroll
  for (int e = 0; e < 8; ++e)
#pragma unroll
    for (int f = 0; f < 8; ++f) {
      atomicAdd(&Cg[(i0+wy+ly+e)*256 + (j0+wx+lx+f)], acc[e][f]);
      if (ty == 1)
        atomicAdd(&Cg[(j0+wx+lx+f)*256 + (i0+wy+ly+e)], acc[e][f]);
    }
}

// ---------------------------------------------------------------------------
// K2: T[bh][i][a] = sum_b Wq[hh*64+i][b] * C[g][b][a].
__global__ __launch_bounds__(256) void k2_T(const float* __restrict__ Wq,
                                            const float* __restrict__ Cmat,
                                            float* __restrict__ T) {
  const int bh = blockIdx.x;
  const int ic = blockIdx.y;
  const int g = bh >> 3, hh = bh & 7;
  const int tid = threadIdx.x;
  const float* __restrict__ Cg = Cmat + (size_t)g * 65536;
  const int r0 = hh * 64 + ic * 4;
  float acc[4] = {0.f, 0.f, 0.f, 0.f};
#pragma unroll 8
  for (int b = 0; b < 256; ++b) {
    const float cv = Cg[(size_t)b * 256 + tid];
#pragma unroll
    for (int ii = 0; ii < 4; ++ii)
      acc[ii] += Wq[(size_t)(r0 + ii) * 256 + b] * cv;
  }
#pragma unroll
  for (int ii = 0; ii < 4; ++ii)
    T[((size_t)bh * 64 + ic * 4 + ii) * 256 + tid] = acc[ii];
}

// ---------------------------------------------------------------------------
// K3: sim[bh][i][j] = 0.125 * sum_a T[bh][i][a] * Wk[hh*64+j][a].
__global__ __launch_bounds__(256) void k3_sim(const float* __restrict__ Wkv,
                                              const float* __restrict__ T,
                                              float* __restrict__ simattn) {
  __shared__ float Ts[64 * 256];
  const int bh = blockIdx.x;
  const int jc = blockIdx.y;
  const int hh = bh & 7;
  const int tid = threadIdx.x;
  {
    const int f4i = tid & 63;
    const int rwb = tid >> 6;
    for (int pass = 0; pass < 16; ++pass) {
      const int row = rwb + pass * 4;
      float4 v = *(const float4*)(T + ((size_t)bh * 64 + row) * 256 + f4i * 4);
      const int a0 = f4i * 4;
      const float vv[4] = {v.x, v.y, v.z, v.w};
#pragma unroll
      for (int e = 0; e < 4; ++e) {
        const int a = a0 + e;
        Ts[row * 256 + (a & ~31) + ((a + row) & 31)] = vv[e];
      }
    }
  }
  __syncthreads();
  const int i  = tid & 63;
  const int jq = tid >> 6;
  const int jb = jc * 16 + jq * 4;
  float acc[4] = {0.f, 0.f, 0.f, 0.f};
#pragma unroll 4
  for (int a = 0; a < 256; ++a) {
    const float tv = Ts[i * 256 + (a & ~31) + ((a + i) & 31)];
#pragma unroll
    for (int jj = 0; jj < 4; ++jj)
      acc[jj] += Wkv[(size_t)(hh * 64 + jb + jj) * 256 + a] * tv;
  }
#pragma unroll
  for (int jj = 0; jj < 4; ++jj)
    simattn[((size_t)bh * 64 + i) * 64 + jb + jj] = acc[jj] * 0.125f;
}

// K3b: row softmax.
__global__ __launch_bounds__(64) void k3b_softmax(float* __restrict__ simattn) {
  const int bh = blockIdx.x;
  const int i  = threadIdx.x;
  float* row = simattn + ((size_t)bh * 64 + i) * 64;
  float v[64];
  float m = -1e30f;
#pragma unroll
  for (int j = 0; j < 64; ++j) { v[j] = row[j]; m = fmaxf(m, v[j]); }
  float s = 0.f;
#pragma unroll
  for (int j = 0; j < 64; ++j) { v[j] = __expf(v[j] - m); s += v[j]; }
  const float inv = 1.0f / s;
#pragma unroll
  for (int j = 0; j < 64; ++j) row[j] = v[j] * inv;
}

// ---------------------------------------------------------------------------
// K4: WeT[g][hh*64+j][co] = sum_i Wout[co][hh*64+i] * attn[bh][i][j].
__global__ __launch_bounds__(256) void k4_we(const float* __restrict__ Wout,
                                             const float* __restrict__ attn,
                                             float* __restrict__ WeT) {
  __shared__ float WL[256 * 64];
  const int jc = blockIdx.x;
  const int hh = blockIdx.y;
  const int g  = blockIdx.z;
  const int bh = g * 8 + hh;
  const int tid = threadIdx.x;
  {
    const int f4i = tid & 15;
    const int cb  = tid >> 4;
    for (int pass = 0; pass < 16; ++pass) {
      const int co = cb + pass * 16;
      float4 v = *(const float4*)(Wout + (size_t)co * 512 + hh * 64 + f4i * 4);
      const int a0 = f4i * 4;
      const float vv[4] = {v.x, v.y, v.z, v.w};
#pragma unroll
      for (int e = 0; e < 4; ++e)
        WL[co * 64 + ((a0 + e + co) & 63)] = vv[e];
    }
  }
  __syncthreads();
  const int jb = jc * 8;
  float acc[8] = {0.f, 0.f, 0.f, 0.f, 0.f, 0.f, 0.f, 0.f};
#pragma unroll 4
  for (int i = 0; i < 64; ++i) {
    const float wv = WL[tid * 64 + ((i + tid) & 63)];
#pragma unroll
    for (int je = 0; je < 8; ++je)
      acc[je] += attn[((size_t)bh * 64 + i) * 64 + jb + je] * wv;
  }
#pragma unroll
  for (int je = 0; je < 8; ++je)
    WeT[(size_t)g * 131072 + (size_t)(hh * 64 + jb + je) * 256 + tid] =
        acc[je];
}

// ---------------------------------------------------------------------------
// K5a (split-o): Mp[g][oc][b][co] = sum_{o in oc-slice of 32} WeT[o][co]*Wv[o][b].
// R7 post-mortem: serial k5 was 56 us at 128 blocks / VALUBusy 1.5% — pure
// latency, half the CUs idle.  2048 blocks, 32-iter loop, partials+reduce.
__global__ __launch_bounds__(256)
void k5a_part(const float* __restrict__ Wkv, const float* __restrict__ WeT,
              float* __restrict__ Mp) {
  const int bc = blockIdx.x;   // 64 -> 4 b each
  const int oc = blockIdx.y;   // 16 o-slices of 32
  const int g  = blockIdx.z;
  const int tid = threadIdx.x;  // co lane
  const int b0 = bc * 4;
  const float* __restrict__ Weg = WeT + (size_t)g * 131072;
  float acc[4] = {0.f, 0.f, 0.f, 0.f};
#pragma unroll 8
  for (int u = 0; u < 32; ++u) {
    const int o = oc * 32 + u;
    const float wv = Weg[(size_t)o * 256 + tid];
    const float* __restrict__ vr = Wkv + (size_t)(512 + o) * 256 + b0;
    acc[0] += vr[0] * wv;
    acc[1] += vr[1] * wv;
    acc[2] += vr[2] * wv;
    acc[3] += vr[3] * wv;
  }
#pragma unroll
  for (int be = 0; be < 4; ++be)
    Mp[(((size_t)g * 16 + oc) * 256 + b0 + be) * 256 + tid] = acc[be];
}

// K5b: reduce 16 o-slice partials -> Mt fp32 [b][co] and MA bf16 [co][b].
__global__ __launch_bounds__(256)
void k5b_red(const float* __restrict__ Mp, float* __restrict__ Mt,
             u16* __restrict__ MA) {
  const int b = blockIdx.x;    // 256
  const int g = blockIdx.y;
  const int tid = threadIdx.x; // co
  const float* __restrict__ P =
      Mp + ((size_t)g * 16 * 256 + b) * 256 + tid;
  float v = 0.f;
#pragma unroll
  for (int oc = 0; oc < 16; ++oc) v += P[(size_t)oc * 65536];
  Mt[(size_t)g * 65536 + (size_t)b * 256 + tid] = v;
  MA[(size_t)g * 65536 + (size_t)tid * 256 + b] = f2bf(v);
}

// Tier-3 serial k5 (tiny ws; known-good).
__global__ __launch_bounds__(256) void k5_serial(const float* __restrict__ Wkv,
                                                 const float* __restrict__ WeT,
                                                 float* __restrict__ Mt,
                                                 u16* __restrict__ MA) {
  const int bc = blockIdx.x;
  const int g  = blockIdx.y;
  const int tid = threadIdx.x;
  const int b0 = bc * 4;
  const float* __restrict__ Weg = WeT + (size_t)g * 131072;
  float acc[4] = {0.f, 0.f, 0.f, 0.f};
#pragma unroll 4
  for (int o = 0; o < 512; ++o) {
    const float wv = Weg[(size_t)o * 256 + tid];
    const float* __restrict__ vr = Wkv + (size_t)(512 + o) * 256 + b0;
    acc[0] += vr[0] * wv;
    acc[1] += vr[1] * wv;
    acc[2] += vr[2] * wv;
    acc[3] += vr[3] * wv;
  }
#pragma unroll
  for (int be = 0; be < 4; ++be) {
    Mt[(size_t)g * 65536 + (size_t)(b0 + be) * 256 + tid] = acc[be];
    MA[(size_t)g * 65536 + (size_t)tid * 256 + b0 + be] = f2bf(acc[be]);
  }
}

// ---------------------------------------------------------------------------
// K6 (MFMA): D[p][co] = sum_f XbT[p][f]*M_A[co][f]; out[co][p] = D + bout[co].
__global__ __launch_bounds__(256)
void k6_mfma(const u16* __restrict__ XbT, const u16* __restrict__ MA,
             const float* __restrict__ bout, float* __restrict__ out) {
  const int pb = blockIdx.x;   // 128 p-blocks of 128
  const int cb = blockIdx.y;   // 2 co-blocks of 128
  const int g  = blockIdx.z;
  const int tid = threadIdx.x;
  const int w = tid >> 6, half = (tid >> 5) & 1, lc = tid & 31;
  const int p0  = pb * 128 + w * 32;
  const int co0 = cb * 128;
  const u16* __restrict__ Ap =
      XbT + ((size_t)g * NP + p0 + lc) * 256 + half * 8;
  const u16* __restrict__ Mg = MA + (size_t)g * 65536;
  f32x16 acc[4];
#pragma unroll
  for (int t = 0; t < 4; ++t)
#pragma unroll
    for (int i = 0; i < 16; ++i) acc[t][i] = 0.f;
#pragma unroll 2
  for (int s = 0; s < 16; ++s) {
    bf16x8 a = ldbf16x8(Ap + s * 16);
#pragma unroll
    for (int t = 0; t < 4; ++t) {
      bf16x8 b =
          ldbf16x8(Mg + (size_t)(co0 + t * 32 + lc) * 256 + half * 8 + s * 16);
      acc[t] = __builtin_amdgcn_mfma_f32_32x32x16_bf16(a, b, acc[t], 0, 0, 0);
    }
  }
#pragma unroll
  for (int t = 0; t < 4; ++t) {
    const int co = co0 + t * 32 + lc;
    const float bo = bout[co];
    float* __restrict__ ocol =
        out + ((size_t)(g * 256 + co)) * NP + p0 + 4 * half;
#pragma unroll
    for (int rg = 0; rg < 4; ++rg) {
      float4 v = {acc[t][rg * 4 + 0] + bo, acc[t][rg * 4 + 1] + bo,
                  acc[t][rg * 4 + 2] + bo, acc[t][rg * 4 + 3] + bo};
      *(float4*)(ocol + rg * 8) = v;
    }
  }
}

// Fallback fp32 K6 (R6 version).
__global__ __launch_bounds__(256)
void k6_apply(const float* __restrict__ x, const float* __restrict__ Mt,
              const float* __restrict__ bout, float* __restrict__ out) {
  __shared__ float As[32 * 132];
  __shared__ float Bs[32 * 132];
  const int pc = blockIdx.x;
  const int oy = blockIdx.y;
  const int g  = blockIdx.z;
  const int p0 = pc * 128;
  const int o0 = oy * 128;
  const float* __restrict__ Xg = x + (size_t)g * 256 * NP;
  const float* __restrict__ Mg = Mt + (size_t)g * 65536;
  const int tid  = threadIdx.x;
  const int lane = tid & 63;
  const int w    = tid >> 6;
  const int wy = (w >> 1) * 64;
  const int wx = (w & 1) * 64;
  const int ly = (lane >> 3) * 8;
  const int lx = (lane & 7) * 8;
  float acc[8][8];
#pragma unroll
  for (int e = 0; e < 8; ++e)
#pragma unroll
    for (int f = 0; f < 8; ++f) acc[e][f] = 0.f;
  const int c4 = (tid & 31) * 4;
  const int kb = tid >> 5;
  for (int s = 0; s < 8; ++s) {
#pragma unroll
    for (int r = 0; r < 4; ++r) {
      const int kk = kb + r * 8;
      const int f  = s * 32 + kk;
      *(float4*)&As[kk * 132 + c4] =
          *(const float4*)(Mg + (size_t)f * 256 + o0 + c4);
      *(float4*)&Bs[kk * 132 + c4] =
          *(const float4*)(Xg + (size_t)f * NP + p0 + c4);
    }
    __syncthreads();
#pragma unroll 4
    for (int kk = 0; kk < 32; ++kk) {
      const float* __restrict__ ar = &As[kk * 132 + wy + ly];
      const float* __restrict__ br = &Bs[kk * 132 + wx + lx];
      float4 a0 = *(const float4*)(ar);
      float4 a1 = *(const float4*)(ar + 4);
      float4 b0 = *(const float4*)(br);
      float4 b1 = *(const float4*)(br + 4);
      const float av[8] = {a0.x, a0.y, a0.z, a0.w, a1.x, a1.y, a1.z, a1.w};
      const float bv[8] = {b0.x, b0.y, b0.z, b0.w, b1.x, b1.y, b1.z, b1.w};
#pragma unroll
      for (int e = 0; e < 8; ++e)
#pragma unroll
        for (int f = 0; f < 8; ++f) acc[e][f] += av[e] * bv[f];
    }
    __syncthreads();
  }
#pragma unroll
  for (int e = 0; e < 8; ++e) {
    const int co = o0 + wy + ly + e;
    const float bo = bout[co];
    float* __restrict__ orow =
        out + ((size_t)(g * 256 + co)) * NP + p0 + wx + lx;
    float4 s0 = {acc[e][0] + bo, acc[e][1] + bo, acc[e][2] + bo,
                 acc[e][3] + bo};
    float4 s1 = {acc[e][4] + bo, acc[e][5] + bo, acc[e][6] + bo,
                 acc[e][7] + bo};
    *(float4*)(orow)     = s0;
    *(float4*)(orow + 4) = s1;
  }
}

// ---------------------------------------------------------------------------
extern "C" void kernel_launch(void* const* d_in, const int* in_sizes, int n_in,
                              void* d_out, int out_size, void* d_ws,
                              size_t ws_size, hipStream_t stream) {
  const float* x    = (const float*)d_in[0];
  const float* Wq   = (const float*)d_in[1];
  const float* Wkv  = (const float*)d_in[2];
  const float* Wout = (const float*)d_in[3];
  const float* bout = (const float*)d_in[4];
  float* out = (float*)d_out;
  float* ws  = (float*)d_ws;

  float* C    = ws + OFF_C;
  float* T    = ws + OFF_T;
  float* att  = ws + OFF_AT;
  float* WeT  = ws + OFF_WE;
  float* Mt   = ws + OFF_MT;
  u16*   MA   = (u16*)(ws + OFF_MA);
  u16*   Xb   = (u16*)(ws + OFF_XB);
  u16*   XbT  = (u16*)(ws + OFF_XBT);
  float* Cp1  = ws + OFF_CP1;
  float* Cp2  = ws + OFF_CP2;

  const bool mfma_path = (ws_size >= NEED1);
  const bool splitk    = (ws_size >= NEED2);

  if (mfma_path) {
    k0_cvt<<<dim3(256, 2), 256, 0, stream>>>(x, Xb, XbT);
    k1_mfma<<<dim3(16, 16, 2), 256, 0, stream>>>(Xb, Cp1);
    k1b_red<<<dim3(16, 16, 2), 256, 0, stream>>>(Cp1, C);
  } else if (splitk) {
    k1_gram<<<dim3(64, 3, 2), 256, 0, stream>>>(x, Cp2);
    k1b_reduce<<<dim3(64, 3, 2), 256, 0, stream>>>(Cp2, C);
  } else {
    hipMemsetAsync(C, 0, 131072 * sizeof(float), stream);
    k1_gram_atomic<<<dim3(64, 3, 2), 256, 0, stream>>>(x, C);
  }
  k2_T<<<dim3(16, 16), 256, 0, stream>>>(Wq, C, T);
  k3_sim<<<dim3(16, 4), 256, 0, stream>>>(Wkv, T, att);
  k3b_softmax<<<dim3(16), 64, 0, stream>>>(att);
  k4_we<<<dim3(8, 8, 2), 256, 0, stream>>>(Wout, att, WeT);
  // k5: split-o partials into the (now free) k1 partial slab, then reduce.
  if (mfma_path) {
    k5a_part<<<dim3(64, 16, 2), 256, 0, stream>>>(Wkv, WeT, Cp1);
    k5b_red<<<dim3(256, 2), 256, 0, stream>>>(Cp1, Mt, MA);
  } else if (splitk) {
    k5a_part<<<dim3(64, 16, 2), 256, 0, stream>>>(Wkv, WeT, Cp2);
    k5b_red<<<dim3(256, 2), 256, 0, stream>>>(Cp2, Mt, MA);
  } else {
    k5_serial<<<dim3(64, 2), 256, 0, stream>>>(Wkv, WeT, Mt, MA);
  }
  if (mfma_path) {
    k6_mfma<<<dim3(128, 2, 2), 256, 0, stream>>>(XbT, MA, bout, out);
  } else {
    k6_apply<<<dim3(128, 2, 2), 256, 0, stream>>>(x, Mt, bout, out);
  }
}